// Round 20
// baseline (739.012 us; speedup 1.0000x reference)
//
#include <hip/hip_runtime.h>
#include <math.h>

#define HH 480
#define WW 640
#define HWSZ (HH*WW)        // 307200
#define NPC 22432
#define IMG_SZ (128*HWSZ)   // 39321600
#define NBP 64              // gram pcd partial blocks
#define CHUNK_P 351         // 64*351 = 22464 >= 22432

typedef unsigned short u16;
typedef unsigned int u32;
typedef __attribute__((ext_vector_type(8))) short bf16x8;
typedef __attribute__((ext_vector_type(4))) float f32x4;

// ws float offsets
#define OFF_SUMS_IMG 0
#define OFF_SUMS_PCD 128
#define OFF_BIAS2    256
#define OFF_COV_IMG  512
#define OFF_COV_PCD  16896
#define OFF_INV_IMG  33280
#define OFF_INV_PCD  49664
#define OFF_MT_IMG   66048
#define OFF_MT_PCD   82432
#define OFF_LWT      98816
#define OFF_PSUMS    115200     // 256*128 = 32768
#define OFF_MB       147968     // M_img bf16 fragments: 16384 u16 = 4096 floats
#define OFF_WT       152064     // 128*9*128 fp32 (fallback conv) = 147456
#define OFF_PSUMS_P  OFF_WT     // pcd psums (64*128) reuse WT region (dead after conv)
#define OFF_PART_IMG 299520     // 256*16384 = 4194304
#define OFF_PART_PCD 4493824    // NBP*16384 = 1048576
#define OFF_WB       5542400    // 9*128*128 bf16 = 73728 floats (fragment layout)
#define OFF_TIMG_F   5616128    // 4 planes x 309444 px x 32c bf16 = 19804416 floats
#define OFF_PART2    OFF_TIMG_F             // 256*16384 floats (aliases dead Timg)
#define OFF_PSUMS2   (OFF_TIMG_F + 4194304) // 256*128 floats (aliases dead Timg)
#define TIMG_PAD_W 642
#define TIMG_PX (482*642)       // 309444
#define TIMG_PLANE (TIMG_PX*32) // u16 per ci-quarter plane
#define WS_NEED_FLOATS 25420544
#define OFF_XB       25420544   // X bf16 [128][307200] u16 = 19660800 floats
#define WS_NEED2_FLOATS 45081344

__device__ inline u32 pack_bf16(float a, float b) {
  u32 ua = __float_as_uint(a), ub = __float_as_uint(b);
  ua += 0x7FFFu + ((ua >> 16) & 1u);
  ub += 0x7FFFu + ((ub >> 16) & 1u);
  return (ua >> 16) | (ub & 0xFFFF0000u);
}
__device__ inline u16 to_bf16(float v) {
  u32 u = __float_as_uint(v); u += 0x7FFFu + ((u >> 16) & 1u);
  return (u16)(u >> 16);
}
__device__ inline float from_bf16(u16 v) {
  return __uint_as_float(((u32)v) << 16);
}
__device__ inline float4 f4_fnma(float4 v, float f, float4 p) {
  return make_float4(v.x - f*p.x, v.y - f*p.y, v.z - f*p.z, v.w - f*p.w);
}
__device__ inline void gload_lds16(const void* g, void* l) {
  __builtin_amdgcn_global_load_lds(
      (const __attribute__((address_space(1))) void*)(g),
      (__attribute__((address_space(3))) void*)(l), 16, 0, 0);
}

// ---------------- prep: fold BN into conv weights (fragment layout) ------------
__global__ void prep_kernel(const float* __restrict__ conv_w, const float* __restrict__ conv_b,
                            const float* __restrict__ gamma, const float* __restrict__ beta,
                            const float* __restrict__ mean, const float* __restrict__ var,
                            const float* __restrict__ lin_w, float* __restrict__ ws, int big) {
  int tid = blockIdx.x * blockDim.x + threadIdx.x;
  int nth = gridDim.x * blockDim.x;
  for (int oc = tid; oc < 128; oc += nth) {
    float s = gamma[oc] / sqrtf(var[oc] + 1e-5f);
    ws[OFF_BIAS2 + oc] = (conv_b[oc] - mean[oc]) * s + beta[oc];
  }
  if (big) {
    u16* Wf = (u16*)(ws + OFF_WB);
    for (int e = tid; e < 9*128*128; e += nth) {
      int j = e & 7, l = (e >> 3) & 63, ob = (e >> 9) & 7;
      int ci32 = (e >> 12) & 3, tap = e >> 14;
      int oc = ob*16 + (l & 15);
      int ci = ci32*32 + ((l >> 4) & 3)*8 + j;
      float s = gamma[oc] / sqrtf(var[oc] + 1e-5f);
      Wf[e] = to_bf16(conv_w[(oc*128 + ci)*9 + tap] * s);
    }
  } else {
    for (int e = tid; e < 128*9*128; e += nth) {
      int oc = e & 127; int k = (e >> 7) % 9; int ci = e / 1152;
      float s = gamma[oc] / sqrtf(var[oc] + 1e-5f);
      ws[OFF_WT + e] = conv_w[(oc*128 + ci)*9 + k] * s;
    }
  }
  for (int e = tid; e < 128*128; e += nth) {
    int c2 = e & 127; int k = e >> 7;
    ws[OFF_LWT + e] = lin_w[c2*128 + k];
  }
}

// ---- img fp32 -> Timg bf16, 4 ci-quarter planes, units XOR-permuted by (w>>2)&3
__launch_bounds__(256)
__global__ void timg_kernel(const float* __restrict__ img, u16* __restrict__ Timg) {
  __shared__ float xt[64][133];
  const int b = blockIdx.x;
  const int t = threadIdx.x;
  if (b >= 4800) {
    int tid = (b - 4800) * 256 + t;
    if (tid < (642*2 + 480*2) * 16) {
      int px = tid >> 4, u = tid & 15;
      int q = u >> 2, j = u & 3;
      int addr;
      if (px < 642) addr = px;
      else if (px < 1284) addr = 481*642 + (px - 642);
      else if (px < 1764) addr = (px - 1284 + 1) * 642;
      else addr = (px - 1764 + 1) * 642 + 641;
      ((uint4*)Timg)[(size_t)q*(TIMG_PX*4) + (size_t)addr*4 + j] = make_uint4(0u,0u,0u,0u);
    }
    return;
  }
  const int h = b / 10, w0 = (b % 10) * 64;
  const int wq = t & 15, cg = t >> 4;
#pragma unroll
  for (int i = 0; i < 8; ++i) {
    int ci = cg + i*16;
    float4 v = *(const float4*)&img[(size_t)ci*HWSZ + h*WW + w0 + wq*4];
    xt[wq*4+0][ci] = v.x; xt[wq*4+1][ci] = v.y;
    xt[wq*4+2][ci] = v.z; xt[wq*4+3][ci] = v.w;
  }
  __syncthreads();
  const int wp = t >> 2, q = t & 3, c0 = q * 32;
  u32 out[16];
#pragma unroll
  for (int j = 0; j < 16; ++j) {
    float a = xt[wp][c0 + 2*j], bb = xt[wp][c0 + 2*j + 1];
    out[j] = pack_bf16(a, bb);
  }
  uint4 ud[4];
#pragma unroll
  for (int u = 0; u < 4; ++u)
    ud[u] = make_uint4(out[u*4], out[u*4+1], out[u*4+2], out[u*4+3]);
  u16* dst = Timg + (size_t)q*TIMG_PLANE
           + ((size_t)(h+1)*TIMG_PAD_W + (w0 + 1 + wp)) * 32;
  const int key = ((1 + wp) >> 2) & 3;
  uint4* d4 = (uint4*)dst;
  switch (key) {
    case 0: d4[0]=ud[0]; d4[1]=ud[1]; d4[2]=ud[2]; d4[3]=ud[3]; break;
    case 1: d4[0]=ud[1]; d4[1]=ud[0]; d4[2]=ud[3]; d4[3]=ud[2]; break;
    case 2: d4[0]=ud[2]; d4[1]=ud[3]; d4[2]=ud[0]; d4[3]=ud[1]; break;
    default: d4[0]=ud[3]; d4[1]=ud[2]; d4[2]=ud[1]; d4[3]=ud[0]; break;
  }
}

// -------- conv (r16 best): double-buffered gload_lds, scrap-clamped tail -------
#define REG_ROWS 6
#define REG_COLS 66
#define REG_PX (REG_ROWS*REG_COLS)   // 396
#define STAGE_E (REG_PX*4)           // 1584
#define BUF_E 1792                    // entries per buffer incl. scrap
__launch_bounds__(256, 2)
__global__ void conv_mfma8_kernel(const u16* __restrict__ Timg,
                                  const u16* __restrict__ Wf,
                                  const float* __restrict__ ws,
                                  float* __restrict__ X,
                                  u16* __restrict__ xb) {
  __shared__ __align__(16) u16 reg_lds[2][BUF_E * 8];   // 57344 B total
  const int b = blockIdx.x;
  const int h0 = (b / 10) * 4;
  const int w0 = (b % 10) * 64;
  const int t = threadIdx.x;
  const int wv = t >> 6, l = t & 63;
  const int n_lane = l & 15, k_lane = l >> 4;
  const int ocg = wv & 1;
  const int rowg = wv >> 1;

  f32x4 acc[4][8];
#pragma unroll
  for (int mt = 0; mt < 4; ++mt)
#pragma unroll
    for (int nt = 0; nt < 8; ++nt) acc[mt][nt] = (f32x4){0.f,0.f,0.f,0.f};

  {
    const u16* plane = Timg;
#pragma unroll
    for (int i = 0; i < 7; ++i) {
      int e = t + i*256;
      int ec = (e < STAGE_E) ? e : (STAGE_E - 1);
      int px = ec >> 2, j = ec & 3;
      int r = px / REG_COLS, c = px - r * REG_COLS;
      const u16* src = plane + ((size_t)(h0 + r) * TIMG_PAD_W + (w0 + c)) * 32 + j*8;
      gload_lds16(src, reg_lds[0] + (size_t)e * 8);
    }
  }
  __syncthreads();

  int cur = 0;
#pragma unroll 1
  for (int qc = 0; qc < 4; ++qc) {
    if (qc < 3) {
      const u16* plane = Timg + (size_t)(qc+1) * TIMG_PLANE;
      u16* dstb = reg_lds[cur ^ 1];
#pragma unroll
      for (int i = 0; i < 7; ++i) {
        int e = t + i*256;
        int ec = (e < STAGE_E) ? e : (STAGE_E - 1);
        int px = ec >> 2, j = ec & 3;
        int r = px / REG_COLS, c = px - r * REG_COLS;
        const u16* src = plane + ((size_t)(h0 + r) * TIMG_PAD_W + (w0 + c)) * 32 + j*8;
        gload_lds16(src, dstb + (size_t)e * 8);
      }
    }
    const u16* curb = reg_lds[cur];
    const u16* wq = Wf + (qc*8 + ocg*4)*512 + l*8;
#pragma unroll 1
    for (int tap = 0; tap < 9; ++tap) {
      const int kh = (tap * 11) >> 5;
      const int kw = tap - kh * 3;
      const int cb = n_lane + kw;
      const int rb = rowg*2 + kh;
      const int uoff = (k_lane ^ ((cb >> 2) & 3)) << 4;
      const u16* wtap = wq + tap * 16384;
      bf16x8 Af[4], Bf[8];
#pragma unroll
      for (int mt = 0; mt < 4; ++mt)
        Af[mt] = *(const bf16x8*)(wtap + mt*512);
#pragma unroll
      for (int nt = 0; nt < 8; ++nt) {
        int px = (rb + (nt >> 2)) * REG_COLS + cb + (nt & 3) * 16;
        Bf[nt] = *(const bf16x8*)((const char*)curb + px * 64 + uoff);
      }
#pragma unroll
      for (int mt = 0; mt < 4; ++mt)
#pragma unroll
        for (int nt = 0; nt < 8; ++nt)
          acc[mt][nt] = __builtin_amdgcn_mfma_f32_16x16x32_bf16(Af[mt], Bf[nt], acc[mt][nt], 0, 0, 0);
    }
    __syncthreads();
    cur ^= 1;
  }
  const float* bias = ws + OFF_BIAS2;
  if (xb) {
#pragma unroll
    for (int mt = 0; mt < 4; ++mt) {
      f32x4 bv = *(const f32x4*)(bias + ocg*64 + mt*16 + k_lane*4);
#pragma unroll
      for (int nt = 0; nt < 8; ++nt) {
        int row = h0 + rowg*2 + (nt >> 2);
        int col = w0 + (nt & 3)*16 + n_lane;
#pragma unroll
        for (int rr = 0; rr < 4; ++rr) {
          int oc = ocg*64 + mt*16 + k_lane*4 + rr;
          float v = acc[mt][nt][rr] + bv[rr];
          xb[(size_t)oc * HWSZ + row*WW + col] = to_bf16(fmaxf(v, 0.f));
        }
      }
    }
  } else {
#pragma unroll
    for (int mt = 0; mt < 4; ++mt) {
      f32x4 bv = *(const f32x4*)(bias + ocg*64 + mt*16 + k_lane*4);
#pragma unroll
      for (int nt = 0; nt < 8; ++nt) {
        int row = h0 + rowg*2 + (nt >> 2);
        int col = w0 + (nt & 3)*16 + n_lane;
#pragma unroll
        for (int rr = 0; rr < 4; ++rr) {
          int oc = ocg*64 + mt*16 + k_lane*4 + rr;
          float v = acc[mt][nt][rr] + bv[rr];
          X[(size_t)oc * HWSZ + row*WW + col] = fmaxf(v, 0.f);
        }
      }
    }
  }
}

// ---------------- fp32 fallback conv -------------------------------------------
__launch_bounds__(256)
__global__ void conv_kernel(const float* __restrict__ img,
                            const float* __restrict__ ws,
                            float* __restrict__ outX) {
  __shared__ __align__(16) float xs[8][10][20];
  __shared__ __align__(16) float wsm[8][9][64];
  const int b = blockIdx.x;
  const int oc0 = (b & 1) * 64;
  const int sidx = b >> 1;
  const int h0 = (sidx / 40) * 8;
  const int w0 = (sidx % 40) * 16;
  const int t = threadIdx.x;
  const int oc_t = t & 15;
  const int px_t = t >> 4;
  const int ph = px_t >> 1;
  const int pw0 = (px_t & 1) * 8;
  float acc[4][8];
#pragma unroll
  for (int o = 0; o < 4; o++)
#pragma unroll
    for (int m = 0; m < 8; m++) acc[o][m] = 0.f;
  const float* wT = ws + OFF_WT;
  for (int ci0 = 0; ci0 < 128; ci0 += 8) {
    __syncthreads();
    for (int e = t; e < 1440; e += 256) {
      int ci = e / 180; int rem = e - ci*180; int r = rem / 18; int cc2 = rem - r*18;
      int gh = h0 + r - 1, gw = w0 + cc2 - 1;
      float v = 0.f;
      if ((unsigned)gh < (unsigned)HH && (unsigned)gw < (unsigned)WW)
        v = img[(ci0+ci)*HWSZ + gh*WW + gw];
      xs[ci][r][cc2] = v;
    }
    for (int e = t; e < 4608; e += 256) {
      int oc = e & 63; int k = (e >> 6) % 9; int ci = e / 576;
      wsm[ci][k][oc] = wT[((ci0+ci)*9 + k)*128 + oc0 + oc];
    }
    __syncthreads();
#pragma unroll
    for (int ci = 0; ci < 8; ci++) {
#pragma unroll
      for (int kh = 0; kh < 3; kh++) {
        float x10[10];
        float4 xa = *(const float4*)&xs[ci][ph+kh][pw0];
        float4 xb2 = *(const float4*)&xs[ci][ph+kh][pw0+4];
        x10[0]=xa.x; x10[1]=xa.y; x10[2]=xa.z; x10[3]=xa.w;
        x10[4]=xb2.x; x10[5]=xb2.y; x10[6]=xb2.z; x10[7]=xb2.w;
        x10[8]=xs[ci][ph+kh][pw0+8]; x10[9]=xs[ci][ph+kh][pw0+9];
#pragma unroll
        for (int kw = 0; kw < 3; kw++) {
          float4 wv = *(const float4*)&wsm[ci][kh*3+kw][oc_t*4];
#pragma unroll
          for (int m = 0; m < 8; m++) {
            float xv = x10[kw+m];
            acc[0][m] += wv.x*xv; acc[1][m] += wv.y*xv;
            acc[2][m] += wv.z*xv; acc[3][m] += wv.w*xv;
          }
        }
      }
    }
  }
#pragma unroll
  for (int o = 0; o < 4; o++) {
    int oc = oc0 + oc_t*4 + o;
    float bias = ws[OFF_BIAS2 + oc];
    float4 r0, r1;
    r0.x = fmaxf(acc[o][0]+bias, 0.f); r0.y = fmaxf(acc[o][1]+bias, 0.f);
    r0.z = fmaxf(acc[o][2]+bias, 0.f); r0.w = fmaxf(acc[o][3]+bias, 0.f);
    r1.x = fmaxf(acc[o][4]+bias, 0.f); r1.y = fmaxf(acc[o][5]+bias, 0.f);
    r1.z = fmaxf(acc[o][6]+bias, 0.f); r1.w = fmaxf(acc[o][7]+bias, 0.f);
    float* dst = outX + (size_t)oc*HWSZ + (h0+ph)*WW + w0 + pw0;
    *(float4*)dst = r0; *(float4*)(dst+4) = r1;
  }
}

// ---------------- linear + ReLU -> Z -------------------------------------------
__launch_bounds__(256)
__global__ void linear_kernel(const float* __restrict__ pcd,
                              const float* __restrict__ ws,
                              const float* __restrict__ lin_b,
                              float* __restrict__ Z) {
  __shared__ __align__(16) float Mt[128][132];
  __shared__ __align__(16) float zs[16][132];
  const int b = blockIdx.x, t = threadIdx.x;
  const int n0 = b * 16;
#pragma unroll
  for (int i = 0; i < 16; i++) {
    int idx = t + i*256; int r = idx >> 5; int c4 = (idx & 31)*4;
    *(float4*)&Mt[r][c4] = *(const float4*)&ws[OFF_LWT + r*128 + c4];
  }
#pragma unroll
  for (int i = 0; i < 2; i++) {
    int idx = t + i*256; int r = idx >> 5; int c4 = (idx & 31)*4;
    *(float4*)&zs[r][c4] = *(const float4*)&pcd[(size_t)(n0+r)*128 + c4];
  }
  __syncthreads();
  const int nl = t & 15;
  const int c0 = (t >> 4) * 8;
  float acc[8];
#pragma unroll
  for (int q = 0; q < 8; q++) acc[q] = 0.f;
#pragma unroll 8
  for (int k = 0; k < 128; k++) {
    float z = zs[nl][k];
    float4 wa = *(const float4*)&Mt[k][c0];
    float4 wb = *(const float4*)&Mt[k][c0+4];
    acc[0]+=z*wa.x; acc[1]+=z*wa.y; acc[2]+=z*wa.z; acc[3]+=z*wa.w;
    acc[4]+=z*wb.x; acc[5]+=z*wb.y; acc[6]+=z*wb.z; acc[7]+=z*wb.w;
  }
  float4 ba = *(const float4*)&lin_b[c0];
  float4 bb = *(const float4*)&lin_b[c0+4];
  float4 r0, r1;
  r0.x = fmaxf(acc[0]+ba.x,0.f); r0.y = fmaxf(acc[1]+ba.y,0.f);
  r0.z = fmaxf(acc[2]+ba.z,0.f); r0.w = fmaxf(acc[3]+ba.w,0.f);
  r1.x = fmaxf(acc[4]+bb.x,0.f); r1.y = fmaxf(acc[5]+bb.y,0.f);
  r1.z = fmaxf(acc[6]+bb.z,0.f); r1.w = fmaxf(acc[7]+bb.w,0.f);
  float* dst = Z + (size_t)(n0+nl)*128 + c0;
  *(float4*)dst = r0; *(float4*)(dst+4) = r1;
}

// ---------------- gram img via MFMA (runtime chunk; 2-region partials) ---------
__launch_bounds__(256)
__global__ void gram_img_mfma_kernel(const float* __restrict__ X,
                                     const u16* __restrict__ xb,
                                     float* __restrict__ part,
                                     float* __restrict__ part2,
                                     float* __restrict__ psums,
                                     float* __restrict__ psums2,
                                     int chunk, int ntiles) {
  __shared__ __align__(16) u16 tile[128*64];   // [c][px64] bf16, XOR-swizzled
  const int b = blockIdx.x, t = threadIdx.x;
  const int px0 = b * chunk;
  const int wv = t >> 6, l = t & 63;
  const int i0 = (wv >> 1) * 64, j0 = (wv & 1) * 64;
  const int row16 = l & 15, kq = l >> 4;
  const int pg = t & 15;
  const int g0 = t >> 4;
  const int cb16 = t >> 1, hb16 = t & 1;
  float csum[8];
#pragma unroll
  for (int q = 0; q < 8; ++q) csum[q] = 0.f;
  f32x4 acc[4][4];
#pragma unroll
  for (int a = 0; a < 4; ++a)
#pragma unroll
    for (int q = 0; q < 4; ++q) acc[a][q] = (f32x4){0.f,0.f,0.f,0.f};

  if (xb) {
    uint4 vcur[4];
#pragma unroll
    for (int gi = 0; gi < 4; ++gi) {
      int g = hb16*4 + gi;
      vcur[gi] = *(const uint4*)(xb + (size_t)cb16*HWSZ + px0 + g*8);
    }
#pragma unroll 1
    for (int ti = 0; ti < ntiles; ++ti) {
      __syncthreads();   // previous MFMA done reading tile
#pragma unroll
      for (int gi = 0; gi < 4; ++gi) {
        int g = hb16*4 + gi;
        *(uint4*)((char*)tile + cb16*128 + ((g*16) ^ ((cb16 & 7) << 4))) = vcur[gi];
        const u16* p16 = (const u16*)&vcur[gi];
#pragma unroll
        for (int j = 0; j < 8; ++j) csum[0] += from_bf16(p16[j]);
      }
      uint4 vnext[4];
#pragma unroll
      for (int gi = 0; gi < 4; ++gi) {
        int g = hb16*4 + gi;
        int plg = (ti+1)*64 + g*8;
        if (ti < ntiles-1 && plg < chunk)
          vnext[gi] = *(const uint4*)(xb + (size_t)cb16*HWSZ + px0 + plg);
        else
          vnext[gi] = make_uint4(0u,0u,0u,0u);
      }
      __syncthreads();
#pragma unroll
      for (int f = 0; f < 2; ++f) {
        bf16x8 Af[4], Bf[4];
#pragma unroll
        for (int mt = 0; mt < 4; ++mt) {
          int c = i0 + mt*16 + row16;
          Af[mt] = *(const bf16x8*)((char*)tile + c*128 + ((f*64 + kq*16) ^ ((c & 7) << 4)));
        }
#pragma unroll
        for (int nt = 0; nt < 4; ++nt) {
          int c = j0 + nt*16 + row16;
          Bf[nt] = *(const bf16x8*)((char*)tile + c*128 + ((f*64 + kq*16) ^ ((c & 7) << 4)));
        }
#pragma unroll
        for (int mt = 0; mt < 4; ++mt)
#pragma unroll
          for (int nt = 0; nt < 4; ++nt)
            acc[mt][nt] = __builtin_amdgcn_mfma_f32_16x16x32_bf16(Af[mt], Bf[nt], acc[mt][nt], 0, 0, 0);
      }
#pragma unroll
      for (int gi = 0; gi < 4; ++gi) vcur[gi] = vnext[gi];
    }
  } else {
#pragma unroll 1
    for (int ti = 0; ti < ntiles; ++ti) {
      const int plg = ti*64 + pg*4;
      float4 v[8];
      if ((ti+1)*64 <= chunk) {
#pragma unroll
        for (int cc = 0; cc < 8; ++cc) {
          int c = g0 + cc*16;
          v[cc] = *(const float4*)(X + (size_t)c*HWSZ + px0 + plg);
        }
      } else {
#pragma unroll
        for (int cc = 0; cc < 8; ++cc) {
          int c = g0 + cc*16;
          const float* src = X + (size_t)c*HWSZ + px0;
#pragma unroll
          for (int j = 0; j < 4; ++j) {
            int p = plg + j;
            ((float*)&v[cc])[j] = (p < chunk) ? src[p] : 0.f;
          }
        }
      }
      __syncthreads();
#pragma unroll
      for (int cc = 0; cc < 8; ++cc) {
        int c = g0 + cc*16;
        csum[cc] += v[cc].x + v[cc].y + v[cc].z + v[cc].w;
        u32 w0 = pack_bf16(v[cc].x, v[cc].y);
        u32 w1 = pack_bf16(v[cc].z, v[cc].w);
        *(uint2*)((char*)tile + c*128 + ((pg*8) ^ ((c & 7) << 4))) = make_uint2(w0, w1);
      }
      __syncthreads();
#pragma unroll
      for (int f = 0; f < 2; ++f) {
        bf16x8 Af[4], Bf[4];
#pragma unroll
        for (int mt = 0; mt < 4; ++mt) {
          int c = i0 + mt*16 + row16;
          Af[mt] = *(const bf16x8*)((char*)tile + c*128 + ((f*64 + kq*16) ^ ((c & 7) << 4)));
        }
#pragma unroll
        for (int nt = 0; nt < 4; ++nt) {
          int c = j0 + nt*16 + row16;
          Bf[nt] = *(const bf16x8*)((char*)tile + c*128 + ((f*64 + kq*16) ^ ((c & 7) << 4)));
        }
#pragma unroll
        for (int mt = 0; mt < 4; ++mt)
#pragma unroll
          for (int nt = 0; nt < 4; ++nt)
            acc[mt][nt] = __builtin_amdgcn_mfma_f32_16x16x32_bf16(Af[mt], Bf[nt], acc[mt][nt], 0, 0, 0);
      }
      __syncthreads();
    }
  }
  float* pd = (b < 256) ? (psums + (size_t)b*128) : (psums2 + (size_t)(b-256)*128);
  if (xb) {
    float s = csum[0];
    s += __shfl_xor(s, 1, 64);
    if ((t & 1) == 0) pd[cb16] = s;
  } else {
#pragma unroll
    for (int cc = 0; cc < 8; ++cc) {
      float s = csum[cc];
      s += __shfl_xor(s, 1, 64);
      s += __shfl_xor(s, 2, 64);
      s += __shfl_xor(s, 4, 64);
      s += __shfl_xor(s, 8, 64);
      if (pg == 0) pd[g0 + cc*16] = s;
    }
  }
  float* dst = (b < 256) ? (part + (size_t)b*16384) : (part2 + (size_t)(b-256)*16384);
#pragma unroll
  for (int mt = 0; mt < 4; ++mt)
#pragma unroll
    for (int nt = 0; nt < 4; ++nt) {
#pragma unroll
      for (int r = 0; r < 4; ++r) {
        int i = i0 + mt*16 + kq*4 + r;
        int j = j0 + nt*16 + row16;
        dst[i*128 + j] = acc[mt][nt][r];
      }
    }
}

// ---------------- gram pcd (fp32) + fused channel partial sums -----------------
__launch_bounds__(256)
__global__ void gram_pcd_kernel(const float* __restrict__ Z, float* __restrict__ part,
                                float* __restrict__ psums_p) {
  __shared__ __align__(16) float zt[64][132];
  __shared__ float ps4[4][32][4];
  const int b = blockIdx.x, t = threadIdx.x;
  const int n0 = b * CHUNK_P;
  const int i0 = (t >> 4) * 8, j0 = (t & 15) * 8;
  float acc[8][8];
#pragma unroll
  for (int a = 0; a < 8; a++)
#pragma unroll
    for (int q = 0; q < 8; q++) acc[a][q] = 0.f;
  float fsum[4] = {0.f, 0.f, 0.f, 0.f};
  for (int tile = 0; tile < 6; tile++) {
    __syncthreads();
#pragma unroll
    for (int i = 0; i < 8; i++) {
      int idx = t + i*256; int r = idx >> 5; int c4 = (idx & 31)*4;
      int lrow = tile*64 + r;
      int n = n0 + lrow;
      float4 v = {0.f,0.f,0.f,0.f};
      if (lrow < CHUNK_P && n < NPC) v = *(const float4*)&Z[(size_t)n*128 + c4];
      *(float4*)&zt[r][c4] = v;
      fsum[0] += v.x; fsum[1] += v.y; fsum[2] += v.z; fsum[3] += v.w;
    }
    __syncthreads();
#pragma unroll 4
    for (int n = 0; n < 64; n++) {
      float4 a0 = *(const float4*)&zt[n][i0];
      float4 a1 = *(const float4*)&zt[n][i0+4];
      float4 b0 = *(const float4*)&zt[n][j0];
      float4 b1 = *(const float4*)&zt[n][j0+4];
      float av[8] = {a0.x,a0.y,a0.z,a0.w,a1.x,a1.y,a1.z,a1.w};
      float bv[8] = {b0.x,b0.y,b0.z,b0.w,b1.x,b1.y,b1.z,b1.w};
#pragma unroll
      for (int a = 0; a < 8; a++)
#pragma unroll
        for (int q = 0; q < 8; q++) acc[a][q] += av[a]*bv[q];
    }
  }
  float* dst = part + (size_t)b*16384;
#pragma unroll
  for (int a = 0; a < 8; a++) {
    float4 w0v = {acc[a][0],acc[a][1],acc[a][2],acc[a][3]};
    float4 w1v = {acc[a][4],acc[a][5],acc[a][6],acc[a][7]};
    *(float4*)&dst[(i0+a)*128 + j0] = w0v;
    *(float4*)&dst[(i0+a)*128 + j0 + 4] = w1v;
  }
  const int wv2 = t >> 6;
#pragma unroll
  for (int j2 = 0; j2 < 4; ++j2) fsum[j2] += __shfl_down(fsum[j2], 32, 64);
  if ((t & 63) < 32) {
#pragma unroll
    for (int j2 = 0; j2 < 4; ++j2) ps4[wv2][t & 31][j2] = fsum[j2];
  }
  __syncthreads();
  if (t < 128) {
    float s = ps4[0][t>>2][t&3] + ps4[1][t>>2][t&3]
            + ps4[2][t>>2][t&3] + ps4[3][t>>2][t&3];
    psums_p[b*128 + t] = s;
  }
}

// ---------------- reduce partials -> cov (channel sums fused) ------------------
__launch_bounds__(128)
__global__ void reduce_cov_kernel(float* __restrict__ ws, int nparts_img) {
  const int b = blockIdx.x, t = threadIdx.x;
  const bool isimg = (b < 128);
  const int i = isimg ? b : b - 128;
  __shared__ float sums[128];
  if (isimg) {
    float s = 0.f;
    for (int p = 0; p < nparts_img; ++p) {
      const float* ps = (p < 256) ? (ws + OFF_PSUMS + (size_t)p*128)
                                  : (ws + OFF_PSUMS2 + (size_t)(p-256)*128);
      s += ps[t];
    }
    sums[t] = s;
  } else {
    const float* psp = ws + OFF_PSUMS_P;
    float s = 0.f;
    for (int p = 0; p < NBP; ++p) s += psp[p*128 + t];
    sums[t] = s;
  }
  __syncthreads();
  float g = 0.f;
  if (isimg) {
    for (int p = 0; p < nparts_img; ++p) {
      const float* part = (p < 256) ? (ws + OFF_PART_IMG + (size_t)p*16384)
                                    : (ws + OFF_PART2 + (size_t)(p-256)*16384);
      g += part[i*128 + t];
    }
  } else {
    const float* part = ws + OFF_PART_PCD;
    for (int p = 0; p < NBP; ++p) g += part[(size_t)p*16384 + i*128 + t];
  }
  float Si = sums[i];
  float Sj = sums[t];
  float n = isimg ? (float)HWSZ : (float)NPC;
  float cov = (g - Si*Sj/n) / (n - 1.f);
  ws[(isimg ? OFF_COV_IMG : OFF_COV_PCD) + i*128 + t] = cov;
}

// ---------------- blocked Gauss-Jordan inverse (panel=16) ----------------------
__launch_bounds__(256, 1)
__global__ void invert_kernel(float* __restrict__ ws) {
  __shared__ float A_[128*132];     // 67584 B
  __shared__ float Rb_[16*132];     // 8448 B
  __shared__ float prw[16];
  __shared__ float pcl[16];
  const int blk = blockIdx.x, t = threadIdx.x;
  const float* src = ws + (blk == 0 ? OFF_COV_IMG : OFF_COV_PCD);
  float* dst = ws + (blk == 0 ? OFF_INV_IMG : OFF_INV_PCD);
  for (int e = t; e < 16384; e += 256) {
    int i = e >> 7, j = e & 127;
    A_[i*132 + j] = src[e] + ((i == j) ? 1e-6f : 0.f);
  }
#pragma unroll 1
  for (int p = 0; p < 8; ++p) {
    const int k0 = p * 16;
    __syncthreads();
    if (t < 64) {
      const int r = t & 15, cg = t >> 4, cb = cg * 4;
      float4 d = *(const float4*)&A_[(k0 + r)*132 + k0 + cb];
#pragma unroll 1
      for (int k = 0; k < 16; ++k) {
        const int kg = k >> 2, km = k & 3;
        if (r == k) {
          prw[cb+0] = d.x; prw[cb+1] = d.y; prw[cb+2] = d.z; prw[cb+3] = d.w;
        }
        if (cg == kg) {
          float el = (km==0) ? d.x : (km==1) ? d.y : (km==2) ? d.z : d.w;
          pcl[r] = el;
        }
        __builtin_amdgcn_wave_barrier();
        float ip = 1.f / pcl[k];
        float f  = pcl[r];
        float p0 = prw[cb+0], p1 = prw[cb+1], p2 = prw[cb+2], p3 = prw[cb+3];
        __builtin_amdgcn_wave_barrier();
        if (r == k) {
          d.x *= ip; d.y *= ip; d.z *= ip; d.w *= ip;
          if (cg == kg) { if (km==0) d.x=ip; else if (km==1) d.y=ip; else if (km==2) d.z=ip; else d.w=ip; }
        } else {
          float g = f * ip;
          d.x -= g*p0; d.y -= g*p1; d.z -= g*p2; d.w -= g*p3;
          if (cg == kg) { if (km==0) d.x=-g; else if (km==1) d.y=-g; else if (km==2) d.z=-g; else d.w=-g; }
        }
        __builtin_amdgcn_wave_barrier();
      }
      *(float4*)&Rb_[r*132 + k0 + cb] = d;
    }
    __syncthreads();
    {
      const int r = t & 15, ch = t >> 4;
      if ((ch >> 1) != p) {
        const int j0 = ch * 8;
        float4 dv0 = *(const float4*)&Rb_[r*132 + k0];
        float4 dv1 = *(const float4*)&Rb_[r*132 + k0 + 4];
        float4 dv2 = *(const float4*)&Rb_[r*132 + k0 + 8];
        float4 dv3 = *(const float4*)&Rb_[r*132 + k0 + 12];
        float dv[16] = {dv0.x,dv0.y,dv0.z,dv0.w, dv1.x,dv1.y,dv1.z,dv1.w,
                        dv2.x,dv2.y,dv2.z,dv2.w, dv3.x,dv3.y,dv3.z,dv3.w};
        float4 a0 = {0,0,0,0}, a1 = {0,0,0,0};
#pragma unroll
        for (int s = 0; s < 16; ++s) {
          float4 r0v = *(const float4*)&A_[(k0+s)*132 + j0];
          float4 r1v = *(const float4*)&A_[(k0+s)*132 + j0 + 4];
          float w = dv[s];
          a0.x += w*r0v.x; a0.y += w*r0v.y; a0.z += w*r0v.z; a0.w += w*r0v.w;
          a1.x += w*r1v.x; a1.y += w*r1v.y; a1.z += w*r1v.z; a1.w += w*r1v.w;
        }
        *(float4*)&Rb_[r*132 + j0] = a0;
        *(float4*)&Rb_[r*132 + j0 + 4] = a1;
      }
    }
    __syncthreads();
    {
      const int tr = t >> 4, tc = t & 15;
      const int r0 = tr * 8, c0 = tc * 8;
      const bool pivrow = (tr >> 1) == p;
      const bool pivcol = (tc >> 1) == p;
      float4 acc[8][2];
      float4 F4[8][4];
      if (pivrow) {
#pragma unroll
        for (int i = 0; i < 8; ++i) {
          acc[i][0] = *(const float4*)&Rb_[(r0 + i - k0)*132 + c0];
          acc[i][1] = *(const float4*)&Rb_[(r0 + i - k0)*132 + c0 + 4];
        }
      } else {
#pragma unroll
        for (int i = 0; i < 8; ++i) {
          F4[i][0] = *(const float4*)&A_[(r0+i)*132 + k0];
          F4[i][1] = *(const float4*)&A_[(r0+i)*132 + k0 + 4];
          F4[i][2] = *(const float4*)&A_[(r0+i)*132 + k0 + 8];
          F4[i][3] = *(const float4*)&A_[(r0+i)*132 + k0 + 12];
        }
        if (pivcol) {
#pragma unroll
          for (int i = 0; i < 8; ++i) {
            acc[i][0] = make_float4(0.f,0.f,0.f,0.f);
            acc[i][1] = make_float4(0.f,0.f,0.f,0.f);
          }
        } else {
#pragma unroll
          for (int i = 0; i < 8; ++i) {
            acc[i][0] = *(const float4*)&A_[(r0+i)*132 + c0];
            acc[i][1] = *(const float4*)&A_[(r0+i)*132 + c0 + 4];
          }
        }
      }
      __syncthreads();
      if (!pivrow) {
#pragma unroll
        for (int s = 0; s < 16; ++s) {
          float4 rb0 = *(const float4*)&Rb_[s*132 + c0];
          float4 rb1 = *(const float4*)&Rb_[s*132 + c0 + 4];
#pragma unroll
          for (int i = 0; i < 8; ++i) {
            float fs = (s&3)==0 ? F4[i][s>>2].x : (s&3)==1 ? F4[i][s>>2].y
                     : (s&3)==2 ? F4[i][s>>2].z : F4[i][s>>2].w;
            acc[i][0] = f4_fnma(acc[i][0], fs, rb0);
            acc[i][1] = f4_fnma(acc[i][1], fs, rb1);
          }
        }
      }
#pragma unroll
      for (int i = 0; i < 8; ++i) {
        *(float4*)&A_[(r0+i)*132 + c0]     = acc[i][0];
        *(float4*)&A_[(r0+i)*132 + c0 + 4] = acc[i][1];
      }
    }
  }
  __syncthreads();
  for (int e = t; e < 16384; e += 256)
    dst[e] = A_[(e >> 7)*132 + (e & 127)];
}

// ---------------- attention rows -> mix matrices (img: bf16 frags, pcd: MT) ----
__launch_bounds__(128)
__global__ void attn_kernel(float* __restrict__ ws) {
  const int b = blockIdx.x, j = threadIdx.x;
  const bool isimg = (b < 128);
  const int i = isimg ? b : b - 128;
  const float* rowA = ws + (isimg ? OFF_COV_PCD : OFF_COV_IMG) + i*128;
  const float* matA = ws + (isimg ? OFF_INV_IMG : OFF_INV_PCD);
  const float* rowB = ws + (isimg ? OFF_COV_IMG : OFF_COV_PCD) + i*128;
  const float* matB = ws + (isimg ? OFF_COV_IMG : OFF_COV_PCD);
  __shared__ float rA[128], rB[128], red[128];
  rA[j] = rowA[j]; rB[j] = rowB[j];
  __syncthreads();
  float dA = 0.f, dB = 0.f;
#pragma unroll 8
  for (int k = 0; k < 128; ++k) {
    dA += rA[k] * matA[k*128 + j];
    dB += rB[k] * matB[k*128 + j];
  }
  dA *= 0.0078125f; dB *= 0.0078125f;
  red[j] = dA; __syncthreads();
  for (int s2 = 64; s2 > 0; s2 >>= 1) { if (j < s2) red[j] = fmaxf(red[j], red[j+s2]); __syncthreads(); }
  float mA = red[0]; __syncthreads();
  float eA = expf(dA - mA);
  red[j] = eA; __syncthreads();
  for (int s2 = 64; s2 > 0; s2 >>= 1) { if (j < s2) red[j] += red[j+s2]; __syncthreads(); }
  float sA = red[0]; __syncthreads();
  red[j] = dB; __syncthreads();
  for (int s2 = 64; s2 > 0; s2 >>= 1) { if (j < s2) red[j] = fmaxf(red[j], red[j+s2]); __syncthreads(); }
  float mB = red[0]; __syncthreads();
  float eB = expf(dB - mB);
  red[j] = eB; __syncthreads();
  for (int s2 = 64; s2 > 0; s2 >>= 1) { if (j < s2) red[j] += red[j+s2]; __syncthreads(); }
  float sB = red[0]; __syncthreads();
  float m = 0.1f * (eA/sA + eB/sB);   // M[i][j]
  if (isimg) {
    int f = j >> 5, ob = i >> 4, l = ((j >> 3) & 3)*16 + (i & 15), jj = j & 7;
    ((u16*)(ws + OFF_MB))[(f*8 + ob)*512 + l*8 + jj] = to_bf16(m);
  } else {
    ws[OFF_MT_PCD + j*128 + i] = m;   // transposed: MT[k][c]
  }
}

// ---------------- img final via MFMA, two-pass transpose (4 blocks/CU) ---------
__launch_bounds__(256, 4)
__global__ void img_final_mfma_kernel(const float* __restrict__ img_in,
                                      const float* __restrict__ ws,
                                      const u16* __restrict__ xb,
                                      float* __restrict__ io) {
  __shared__ __align__(16) char smem[34816];   // max(bt 32768, ts 34816)
  u16* bt = (u16*)smem;          // [128px][128c] bf16, XOR-swizzled
  float* ts = (float*)smem;      // [128c][68px]
  const int blk = blockIdx.x, t = threadIdx.x;
  const int px0 = blk * 128;
  const int pxg = (t & 31) * 4;
  const int cp0 = t >> 5;
  if (xb) {
#pragma unroll
    for (int cc = 0; cc < 8; ++cc) {
      int cpair = cp0 + cc*8;
      const u16* s0 = xb + (size_t)(2*cpair)*HWSZ + px0 + pxg;
      uint2 ua = *(const uint2*)s0;
      uint2 ub = *(const uint2*)(s0 + HWSZ);
      u32 w[4];
      w[0] = (ua.x & 0xFFFFu) | ((ub.x & 0xFFFFu) << 16);
      w[1] = (ua.x >> 16)     | (ub.x & 0xFFFF0000u);
      w[2] = (ua.y & 0xFFFFu) | ((ub.y & 0xFFFFu) << 16);
      w[3] = (ua.y >> 16)     | (ub.y & 0xFFFF0000u);
#pragma unroll
      for (int j = 0; j < 4; ++j) {
        int pxl = pxg + j;
        *(u32*)((char*)bt + pxl*256 + ((cpair*4) ^ ((pxl & 7) << 4))) = w[j];
      }
    }
  } else {
#pragma unroll
    for (int cc = 0; cc < 8; ++cc) {
      int cpair = cp0 + cc*8;
      const float* s0 = io + (size_t)(2*cpair)*HWSZ + px0 + pxg;
      float4 a = *(const float4*)s0;
      float4 b4 = *(const float4*)(s0 + HWSZ);
#pragma unroll
      for (int j = 0; j < 4; ++j) {
        int pxl = pxg + j;
        *(u32*)((char*)bt + pxl*256 + ((cpair*4) ^ ((pxl & 7) << 4))) =
            pack_bf16(((const float*)&a)[j], ((const float*)&b4)[j]);
      }
    }
  }
  __syncthreads();
  const int wv = t >> 6, l = t & 63;
  const int i0 = (wv >> 1) * 64, j0 = (wv & 1) * 64;
  const int row16 = l & 15, kq = l >> 4;
  const u16* Mbf = (const u16*)(ws + OFF_MB);
  f32x4 acc[4][4];
#pragma unroll
  for (int a = 0; a < 4; ++a)
#pragma unroll
    for (int q = 0; q < 4; ++q) acc[a][q] = (f32x4){0.f,0.f,0.f,0.f};
#pragma unroll
  for (int f = 0; f < 4; ++f) {
    bf16x8 Bf[4], Am[4];
#pragma unroll
    for (int nt = 0; nt < 4; ++nt) {
      int pxl = j0 + nt*16 + row16;
      Bf[nt] = *(const bf16x8*)((char*)bt + pxl*256 + ((f*64 + kq*16) ^ ((pxl & 7) << 4)));
    }
#pragma unroll
    for (int mt = 0; mt < 4; ++mt) {
      int ob = (wv >> 1) * 4 + mt;
      Am[mt] = *(const bf16x8*)(Mbf + (f*8 + ob)*512 + l*8);
    }
#pragma unroll
    for (int mt = 0; mt < 4; ++mt)
#pragma unroll
      for (int nt = 0; nt < 4; ++nt)
        acc[mt][nt] = __builtin_amdgcn_mfma_f32_16x16x32_bf16(Am[mt], Bf[nt], acc[mt][nt], 0, 0, 0);
  }
#pragma unroll 1
  for (int half = 0; half < 2; ++half) {
    __syncthreads();
    if ((wv & 1) == half) {
#pragma unroll
      for (int mt = 0; mt < 4; ++mt)
#pragma unroll
        for (int nt = 0; nt < 4; ++nt) {
          int lpx = nt*16 + row16;
#pragma unroll
          for (int r = 0; r < 4; ++r) {
            int c = i0 + mt*16 + kq*4 + r;
            ts[c*68 + lpx] = acc[mt][nt][r];
          }
        }
    }
    __syncthreads();
    const int cq = t >> 2, p4 = (t & 3) * 4;
#pragma unroll
    for (int cp = 0; cp < 2; ++cp) {
      int c = cp*64 + cq;
#pragma unroll
      for (int j = 0; j < 4; ++j) {
        int lpx = p4 + j*16;
        float4 v = *(const float4*)&ts[c*68 + lpx];
        size_t off = (size_t)c*HWSZ + px0 + half*64 + lpx;
        float4 o = *(const float4*)&img_in[off];
        float4 r;
        r.x = v.x + 0.8f*o.x; r.y = v.y + 0.8f*o.y;
        r.z = v.z + 0.8f*o.z; r.w = v.w + 0.8f*o.w;
        *(float4*)&io[off] = r;
      }
    }
  }
}

// ---------------- pcd final: Z = Z @ M_pcd^T + 0.8*pcd (in place) --------------
__launch_bounds__(256)
__global__ void pcd_final_kernel(const float* __restrict__ pcd_in,
                                 const float* __restrict__ ws,
                                 float* __restrict__ Z) {
  __shared__ __align__(16) float Mt[128][132];
  __shared__ __align__(16) float zs[16][132];
  const int b = blockIdx.x, t = threadIdx.x;
  const int n0 = b * 16;
#pragma unroll
  for (int i = 0; i < 16; i++) {
    int idx = t + i*256; int r = idx >> 5; int c4 = (idx & 31)*4;
    *(float4*)&Mt[r][c4] = *(const float4*)&ws[OFF_MT_PCD + r*128 + c4];
  }
#pragma unroll
  for (int i = 0; i < 2; i++) {
    int idx = t + i*256; int r = idx >> 5; int c4 = (idx & 31)*4;
    *(float4*)&zs[r][c4] = *(const float4*)&Z[(size_t)(n0+r)*128 + c4];
  }
  __syncthreads();
  const int nl = t & 15;
  const int c0 = (t >> 4) * 8;
  float acc[8];
#pragma unroll
  for (int q = 0; q < 8; q++) acc[q] = 0.f;
#pragma unroll 8
  for (int k = 0; k < 128; k++) {
    float z = zs[nl][k];
    float4 wa = *(const float4*)&Mt[k][c0];
    float4 wb = *(const float4*)&Mt[k][c0+4];
    acc[0]+=z*wa.x; acc[1]+=z*wa.y; acc[2]+=z*wa.z; acc[3]+=z*wa.w;
    acc[4]+=z*wb.x; acc[5]+=z*wb.y; acc[6]+=z*wb.z; acc[7]+=z*wb.w;
  }
  size_t off = (size_t)(n0+nl)*128 + c0;
  float4 pa = *(const float4*)&pcd_in[off];
  float4 pb = *(const float4*)&pcd_in[off+4];
  float4 r0, r1;
  r0.x = acc[0] + 0.8f*pa.x; r0.y = acc[1] + 0.8f*pa.y;
  r0.z = acc[2] + 0.8f*pa.z; r0.w = acc[3] + 0.8f*pa.w;
  r1.x = acc[4] + 0.8f*pb.x; r1.y = acc[5] + 0.8f*pb.y;
  r1.z = acc[6] + 0.8f*pb.z; r1.w = acc[7] + 0.8f*pb.w;
  *(float4*)&Z[off] = r0; *(float4*)&Z[off+4] = r1;
}

extern "C" void kernel_launch(void* const* d_in, const int* in_sizes, int n_in,
                              void* d_out, int out_size, void* d_ws, size_t ws_size,
                              hipStream_t stream) {
  (void)in_sizes; (void)n_in; (void)out_size;
  const float* img_in = (const float*)d_in[0];
  const float* pcd_in = (const float*)d_in[1];
  const float* conv_w = (const float*)d_in[2];
  const float* conv_b = (const float*)d_in[3];
  const float* gamma  = (const float*)d_in[4];
  const float* beta   = (const float*)d_in[5];
  const float* mean   = (const float*)d_in[6];
  const float* var    = (const float*)d_in[7];
  const float* lin_w  = (const float*)d_in[8];
  const float* lin_b  = (const float*)d_in[9];
  float* out = (float*)d_out;
  float* X = out;            // [128][307200] conv output (fp32 path)
  float* Z = out + IMG_SZ;   // [22432][128] linear output, transformed in place
  float* ws = (float*)d_ws;
  const int big  = (ws_size >= (size_t)WS_NEED_FLOATS * 4) ? 1 : 0;
  const int big2 = (ws_size >= (size_t)WS_NEED2_FLOATS * 4) ? 1 : 0;
  u16* Xb = big2 ? (u16*)(ws + OFF_XB) : (u16*)nullptr;

  hipLaunchKernelGGL(prep_kernel, dim3(64), dim3(256), 0, stream,
                     conv_w, conv_b, gamma, beta, mean, var, lin_w, ws, big);
  if (big) {
    u16* Timg = (u16*)(ws + OFF_TIMG_F);
    u16* Wf = (u16*)(ws + OFF_WB);
    hipLaunchKernelGGL(timg_kernel, dim3(4941), dim3(256), 0, stream, img_in, Timg);
    hipLaunchKernelGGL(conv_mfma8_kernel, dim3(1200), dim3(256), 0, stream, Timg, Wf, ws, X, Xb);
  } else {
    hipLaunchKernelGGL(conv_kernel, dim3(4800), dim3(256), 0, stream, img_in, ws, X);
  }
  hipLaunchKernelGGL(linear_kernel, dim3(NPC/16), dim3(256), 0, stream, pcd_in, ws, lin_b, Z);
  // gram_img: big path uses 512 chunks of 600 px (2 blocks/CU); partials for
  // blocks >=256 alias the dead Timg region (rewritten by timg each replay).
  {
    int nbi    = big ? 512 : 256;
    int chunk  = big ? 600 : 1200;
    int ntiles = big ? 10  : 19;
    hipLaunchKernelGGL(gram_img_mfma_kernel, dim3(nbi), dim3(256), 0, stream,
                       X, Xb, ws + OFF_PART_IMG, ws + OFF_PART2,
                       ws + OFF_PSUMS, ws + OFF_PSUMS2, chunk, ntiles);
    hipLaunchKernelGGL(gram_pcd_kernel, dim3(NBP), dim3(256), 0, stream,
                       Z, ws + OFF_PART_PCD, ws + OFF_PSUMS_P);
    hipLaunchKernelGGL(reduce_cov_kernel, dim3(256), dim3(128), 0, stream, ws, nbi);
  }
  hipLaunchKernelGGL(invert_kernel, dim3(2), dim3(256), 0, stream, ws);
  hipLaunchKernelGGL(attn_kernel, dim3(256), dim3(128), 0, stream, ws);
  hipLaunchKernelGGL(img_final_mfma_kernel, dim3(HWSZ/128), dim3(256), 0, stream,
                     img_in, ws, Xb, X);
  hipLaunchKernelGGL(pcd_final_kernel, dim3(NPC/16), dim3(256), 0, stream, pcd_in, ws, Z);
}

// Round 21
// 480.562 us; speedup vs baseline: 1.5378x; 1.5378x over previous
//
#include <hip/hip_runtime.h>
#include <math.h>

#define HH 480
#define WW 640
#define HWSZ (HH*WW)        // 307200
#define NPC 22432
#define IMG_SZ (128*HWSZ)   // 39321600
#define NBP 64              // gram pcd partial blocks
#define CHUNK_P 351         // 64*351 = 22464 >= 22432

typedef unsigned short u16;
typedef unsigned int u32;
typedef __attribute__((ext_vector_type(8))) short bf16x8;
typedef __attribute__((ext_vector_type(4))) float f32x4;

// ws float offsets
#define OFF_SUMS_IMG 0
#define OFF_SUMS_PCD 128
#define OFF_BIAS2    256
#define OFF_COV_IMG  512
#define OFF_COV_PCD  16896
#define OFF_INV_IMG  33280
#define OFF_INV_PCD  49664
#define OFF_MT_IMG   66048
#define OFF_MT_PCD   82432
#define OFF_LWT      98816
#define OFF_PSUMS    115200     // 256*128 = 32768
#define OFF_MB       147968     // M_img bf16 fragments: 16384 u16 = 4096 floats
#define OFF_WT       152064     // 128*9*128 fp32 (fallback conv) = 147456
#define OFF_PSUMS_P  OFF_WT     // pcd psums (64*128) reuse WT region (dead after conv)
#define OFF_PART_IMG 299520     // 256*16384 = 4194304
#define OFF_PART_PCD 4493824    // NBP*16384 = 1048576
#define OFF_WB       5542400    // 9*128*128 bf16 = 73728 floats (fragment layout)
#define OFF_TIMG_F   5616128    // 4 planes x 309444 px x 32c bf16 = 19804416 floats
#define OFF_PART2    OFF_TIMG_F             // 256*16384 floats (aliases dead Timg)
#define OFF_PSUMS2   (OFF_TIMG_F + 4194304) // 256*128 floats (aliases dead Timg)
#define TIMG_PAD_W 642
#define TIMG_PX (482*642)       // 309444
#define TIMG_PLANE (TIMG_PX*32) // u16 per ci-quarter plane
#define WS_NEED_FLOATS 25420544
#define OFF_XB       25420544   // X bf16 [128][307200] u16 = 19660800 floats
#define WS_NEED2_FLOATS 45081344

__device__ inline u32 pack_bf16(float a, float b) {
  u32 ua = __float_as_uint(a), ub = __float_as_uint(b);
  ua += 0x7FFFu + ((ua >> 16) & 1u);
  ub += 0x7FFFu + ((ub >> 16) & 1u);
  return (ua >> 16) | (ub & 0xFFFF0000u);
}
__device__ inline u16 to_bf16(float v) {
  u32 u = __float_as_uint(v); u += 0x7FFFu + ((u >> 16) & 1u);
  return (u16)(u >> 16);
}
__device__ inline float from_bf16(u16 v) {
  return __uint_as_float(((u32)v) << 16);
}
__device__ inline float4 f4_fnma(float4 v, float f, float4 p) {
  return make_float4(v.x - f*p.x, v.y - f*p.y, v.z - f*p.z, v.w - f*p.w);
}
__device__ inline void gload_lds16(const void* g, void* l) {
  __builtin_amdgcn_global_load_lds(
      (const __attribute__((address_space(1))) void*)(g),
      (__attribute__((address_space(3))) void*)(l), 16, 0, 0);
}

// ---------------- prep: fold BN into conv weights (fragment layout) ------------
__global__ void prep_kernel(const float* __restrict__ conv_w, const float* __restrict__ conv_b,
                            const float* __restrict__ gamma, const float* __restrict__ beta,
                            const float* __restrict__ mean, const float* __restrict__ var,
                            const float* __restrict__ lin_w, float* __restrict__ ws, int big) {
  int tid = blockIdx.x * blockDim.x + threadIdx.x;
  int nth = gridDim.x * blockDim.x;
  for (int oc = tid; oc < 128; oc += nth) {
    float s = gamma[oc] / sqrtf(var[oc] + 1e-5f);
    ws[OFF_BIAS2 + oc] = (conv_b[oc] - mean[oc]) * s + beta[oc];
  }
  if (big) {
    u16* Wf = (u16*)(ws + OFF_WB);
    for (int e = tid; e < 9*128*128; e += nth) {
      int j = e & 7, l = (e >> 3) & 63, ob = (e >> 9) & 7;
      int ci32 = (e >> 12) & 3, tap = e >> 14;
      int oc = ob*16 + (l & 15);
      int ci = ci32*32 + ((l >> 4) & 3)*8 + j;
      float s = gamma[oc] / sqrtf(var[oc] + 1e-5f);
      Wf[e] = to_bf16(conv_w[(oc*128 + ci)*9 + tap] * s);
    }
  } else {
    for (int e = tid; e < 128*9*128; e += nth) {
      int oc = e & 127; int k = (e >> 7) % 9; int ci = e / 1152;
      float s = gamma[oc] / sqrtf(var[oc] + 1e-5f);
      ws[OFF_WT + e] = conv_w[(oc*128 + ci)*9 + k] * s;
    }
  }
  for (int e = tid; e < 128*128; e += nth) {
    int c2 = e & 127; int k = e >> 7;
    ws[OFF_LWT + e] = lin_w[c2*128 + k];
  }
}

// ---- img fp32 -> Timg bf16, 4 ci-quarter planes, units XOR-permuted by (w>>2)&3
__launch_bounds__(256)
__global__ void timg_kernel(const float* __restrict__ img, u16* __restrict__ Timg) {
  __shared__ float xt[64][133];
  const int b = blockIdx.x;
  const int t = threadIdx.x;
  if (b >= 4800) {
    int tid = (b - 4800) * 256 + t;
    if (tid < (642*2 + 480*2) * 16) {
      int px = tid >> 4, u = tid & 15;
      int q = u >> 2, j = u & 3;
      int addr;
      if (px < 642) addr = px;
      else if (px < 1284) addr = 481*642 + (px - 642);
      else if (px < 1764) addr = (px - 1284 + 1) * 642;
      else addr = (px - 1764 + 1) * 642 + 641;
      ((uint4*)Timg)[(size_t)q*(TIMG_PX*4) + (size_t)addr*4 + j] = make_uint4(0u,0u,0u,0u);
    }
    return;
  }
  const int h = b / 10, w0 = (b % 10) * 64;
  const int wq = t & 15, cg = t >> 4;
#pragma unroll
  for (int i = 0; i < 8; ++i) {
    int ci = cg + i*16;
    float4 v = *(const float4*)&img[(size_t)ci*HWSZ + h*WW + w0 + wq*4];
    xt[wq*4+0][ci] = v.x; xt[wq*4+1][ci] = v.y;
    xt[wq*4+2][ci] = v.z; xt[wq*4+3][ci] = v.w;
  }
  __syncthreads();
  const int wp = t >> 2, q = t & 3, c0 = q * 32;
  u32 out[16];
#pragma unroll
  for (int j = 0; j < 16; ++j) {
    float a = xt[wp][c0 + 2*j], bb = xt[wp][c0 + 2*j + 1];
    out[j] = pack_bf16(a, bb);
  }
  uint4 ud[4];
#pragma unroll
  for (int u = 0; u < 4; ++u)
    ud[u] = make_uint4(out[u*4], out[u*4+1], out[u*4+2], out[u*4+3]);
  u16* dst = Timg + (size_t)q*TIMG_PLANE
           + ((size_t)(h+1)*TIMG_PAD_W + (w0 + 1 + wp)) * 32;
  const int key = ((1 + wp) >> 2) & 3;
  uint4* d4 = (uint4*)dst;
  switch (key) {
    case 0: d4[0]=ud[0]; d4[1]=ud[1]; d4[2]=ud[2]; d4[3]=ud[3]; break;
    case 1: d4[0]=ud[1]; d4[1]=ud[0]; d4[2]=ud[3]; d4[3]=ud[2]; break;
    case 2: d4[0]=ud[2]; d4[1]=ud[3]; d4[2]=ud[0]; d4[3]=ud[1]; break;
    default: d4[0]=ud[3]; d4[1]=ud[2]; d4[2]=ud[1]; d4[3]=ud[0]; break;
  }
}

// -------- conv (r16 best): double-buffered gload_lds, scrap-clamped tail -------
#define REG_ROWS 6
#define REG_COLS 66
#define REG_PX (REG_ROWS*REG_COLS)   // 396
#define STAGE_E (REG_PX*4)           // 1584
#define BUF_E 1792                    // entries per buffer incl. scrap
__launch_bounds__(256, 2)
__global__ void conv_mfma8_kernel(const u16* __restrict__ Timg,
                                  const u16* __restrict__ Wf,
                                  const float* __restrict__ ws,
                                  float* __restrict__ X,
                                  u16* __restrict__ xb) {
  __shared__ __align__(16) u16 reg_lds[2][BUF_E * 8];   // 57344 B total
  const int b = blockIdx.x;
  const int h0 = (b / 10) * 4;
  const int w0 = (b % 10) * 64;
  const int t = threadIdx.x;
  const int wv = t >> 6, l = t & 63;
  const int n_lane = l & 15, k_lane = l >> 4;
  const int ocg = wv & 1;
  const int rowg = wv >> 1;

  f32x4 acc[4][8];
#pragma unroll
  for (int mt = 0; mt < 4; ++mt)
#pragma unroll
    for (int nt = 0; nt < 8; ++nt) acc[mt][nt] = (f32x4){0.f,0.f,0.f,0.f};

  {
    const u16* plane = Timg;
#pragma unroll
    for (int i = 0; i < 7; ++i) {
      int e = t + i*256;
      int ec = (e < STAGE_E) ? e : (STAGE_E - 1);
      int px = ec >> 2, j = ec & 3;
      int r = px / REG_COLS, c = px - r * REG_COLS;
      const u16* src = plane + ((size_t)(h0 + r) * TIMG_PAD_W + (w0 + c)) * 32 + j*8;
      gload_lds16(src, reg_lds[0] + (size_t)e * 8);
    }
  }
  __syncthreads();

  int cur = 0;
#pragma unroll 1
  for (int qc = 0; qc < 4; ++qc) {
    if (qc < 3) {
      const u16* plane = Timg + (size_t)(qc+1) * TIMG_PLANE;
      u16* dstb = reg_lds[cur ^ 1];
#pragma unroll
      for (int i = 0; i < 7; ++i) {
        int e = t + i*256;
        int ec = (e < STAGE_E) ? e : (STAGE_E - 1);
        int px = ec >> 2, j = ec & 3;
        int r = px / REG_COLS, c = px - r * REG_COLS;
        const u16* src = plane + ((size_t)(h0 + r) * TIMG_PAD_W + (w0 + c)) * 32 + j*8;
        gload_lds16(src, dstb + (size_t)e * 8);
      }
    }
    const u16* curb = reg_lds[cur];
    const u16* wq = Wf + (qc*8 + ocg*4)*512 + l*8;
#pragma unroll 1
    for (int tap = 0; tap < 9; ++tap) {
      const int kh = (tap * 11) >> 5;
      const int kw = tap - kh * 3;
      const int cb = n_lane + kw;
      const int rb = rowg*2 + kh;
      const int uoff = (k_lane ^ ((cb >> 2) & 3)) << 4;
      const u16* wtap = wq + tap * 16384;
      bf16x8 Af[4], Bf[8];
#pragma unroll
      for (int mt = 0; mt < 4; ++mt)
        Af[mt] = *(const bf16x8*)(wtap + mt*512);
#pragma unroll
      for (int nt = 0; nt < 8; ++nt) {
        int px = (rb + (nt >> 2)) * REG_COLS + cb + (nt & 3) * 16;
        Bf[nt] = *(const bf16x8*)((const char*)curb + px * 64 + uoff);
      }
#pragma unroll
      for (int mt = 0; mt < 4; ++mt)
#pragma unroll
        for (int nt = 0; nt < 8; ++nt)
          acc[mt][nt] = __builtin_amdgcn_mfma_f32_16x16x32_bf16(Af[mt], Bf[nt], acc[mt][nt], 0, 0, 0);
    }
    __syncthreads();
    cur ^= 1;
  }
  const float* bias = ws + OFF_BIAS2;
  if (xb) {
#pragma unroll
    for (int mt = 0; mt < 4; ++mt) {
      f32x4 bv = *(const f32x4*)(bias + ocg*64 + mt*16 + k_lane*4);
#pragma unroll
      for (int nt = 0; nt < 8; ++nt) {
        int row = h0 + rowg*2 + (nt >> 2);
        int col = w0 + (nt & 3)*16 + n_lane;
#pragma unroll
        for (int rr = 0; rr < 4; ++rr) {
          int oc = ocg*64 + mt*16 + k_lane*4 + rr;
          float v = acc[mt][nt][rr] + bv[rr];
          xb[(size_t)oc * HWSZ + row*WW + col] = to_bf16(fmaxf(v, 0.f));
        }
      }
    }
  } else {
#pragma unroll
    for (int mt = 0; mt < 4; ++mt) {
      f32x4 bv = *(const f32x4*)(bias + ocg*64 + mt*16 + k_lane*4);
#pragma unroll
      for (int nt = 0; nt < 8; ++nt) {
        int row = h0 + rowg*2 + (nt >> 2);
        int col = w0 + (nt & 3)*16 + n_lane;
#pragma unroll
        for (int rr = 0; rr < 4; ++rr) {
          int oc = ocg*64 + mt*16 + k_lane*4 + rr;
          float v = acc[mt][nt][rr] + bv[rr];
          X[(size_t)oc * HWSZ + row*WW + col] = fmaxf(v, 0.f);
        }
      }
    }
  }
}

// ---------------- fp32 fallback conv -------------------------------------------
__launch_bounds__(256)
__global__ void conv_kernel(const float* __restrict__ img,
                            const float* __restrict__ ws,
                            float* __restrict__ outX) {
  __shared__ __align__(16) float xs[8][10][20];
  __shared__ __align__(16) float wsm[8][9][64];
  const int b = blockIdx.x;
  const int oc0 = (b & 1) * 64;
  const int sidx = b >> 1;
  const int h0 = (sidx / 40) * 8;
  const int w0 = (sidx % 40) * 16;
  const int t = threadIdx.x;
  const int oc_t = t & 15;
  const int px_t = t >> 4;
  const int ph = px_t >> 1;
  const int pw0 = (px_t & 1) * 8;
  float acc[4][8];
#pragma unroll
  for (int o = 0; o < 4; o++)
#pragma unroll
    for (int m = 0; m < 8; m++) acc[o][m] = 0.f;
  const float* wT = ws + OFF_WT;
  for (int ci0 = 0; ci0 < 128; ci0 += 8) {
    __syncthreads();
    for (int e = t; e < 1440; e += 256) {
      int ci = e / 180; int rem = e - ci*180; int r = rem / 18; int cc2 = rem - r*18;
      int gh = h0 + r - 1, gw = w0 + cc2 - 1;
      float v = 0.f;
      if ((unsigned)gh < (unsigned)HH && (unsigned)gw < (unsigned)WW)
        v = img[(ci0+ci)*HWSZ + gh*WW + gw];
      xs[ci][r][cc2] = v;
    }
    for (int e = t; e < 4608; e += 256) {
      int oc = e & 63; int k = (e >> 6) % 9; int ci = e / 576;
      wsm[ci][k][oc] = wT[((ci0+ci)*9 + k)*128 + oc0 + oc];
    }
    __syncthreads();
#pragma unroll
    for (int ci = 0; ci < 8; ci++) {
#pragma unroll
      for (int kh = 0; kh < 3; kh++) {
        float x10[10];
        float4 xa = *(const float4*)&xs[ci][ph+kh][pw0];
        float4 xb2 = *(const float4*)&xs[ci][ph+kh][pw0+4];
        x10[0]=xa.x; x10[1]=xa.y; x10[2]=xa.z; x10[3]=xa.w;
        x10[4]=xb2.x; x10[5]=xb2.y; x10[6]=xb2.z; x10[7]=xb2.w;
        x10[8]=xs[ci][ph+kh][pw0+8]; x10[9]=xs[ci][ph+kh][pw0+9];
#pragma unroll
        for (int kw = 0; kw < 3; kw++) {
          float4 wv = *(const float4*)&wsm[ci][kh*3+kw][oc_t*4];
#pragma unroll
          for (int m = 0; m < 8; m++) {
            float xv = x10[kw+m];
            acc[0][m] += wv.x*xv; acc[1][m] += wv.y*xv;
            acc[2][m] += wv.z*xv; acc[3][m] += wv.w*xv;
          }
        }
      }
    }
  }
#pragma unroll
  for (int o = 0; o < 4; o++) {
    int oc = oc0 + oc_t*4 + o;
    float bias = ws[OFF_BIAS2 + oc];
    float4 r0, r1;
    r0.x = fmaxf(acc[o][0]+bias, 0.f); r0.y = fmaxf(acc[o][1]+bias, 0.f);
    r0.z = fmaxf(acc[o][2]+bias, 0.f); r0.w = fmaxf(acc[o][3]+bias, 0.f);
    r1.x = fmaxf(acc[o][4]+bias, 0.f); r1.y = fmaxf(acc[o][5]+bias, 0.f);
    r1.z = fmaxf(acc[o][6]+bias, 0.f); r1.w = fmaxf(acc[o][7]+bias, 0.f);
    float* dst = outX + (size_t)oc*HWSZ + (h0+ph)*WW + w0 + pw0;
    *(float4*)dst = r0; *(float4*)(dst+4) = r1;
  }
}

// ---------------- linear + ReLU -> Z -------------------------------------------
__launch_bounds__(256)
__global__ void linear_kernel(const float* __restrict__ pcd,
                              const float* __restrict__ ws,
                              const float* __restrict__ lin_b,
                              float* __restrict__ Z) {
  __shared__ __align__(16) float Mt[128][132];
  __shared__ __align__(16) float zs[16][132];
  const int b = blockIdx.x, t = threadIdx.x;
  const int n0 = b * 16;
#pragma unroll
  for (int i = 0; i < 16; i++) {
    int idx = t + i*256; int r = idx >> 5; int c4 = (idx & 31)*4;
    *(float4*)&Mt[r][c4] = *(const float4*)&ws[OFF_LWT + r*128 + c4];
  }
#pragma unroll
  for (int i = 0; i < 2; i++) {
    int idx = t + i*256; int r = idx >> 5; int c4 = (idx & 31)*4;
    *(float4*)&zs[r][c4] = *(const float4*)&pcd[(size_t)(n0+r)*128 + c4];
  }
  __syncthreads();
  const int nl = t & 15;
  const int c0 = (t >> 4) * 8;
  float acc[8];
#pragma unroll
  for (int q = 0; q < 8; q++) acc[q] = 0.f;
#pragma unroll 8
  for (int k = 0; k < 128; k++) {
    float z = zs[nl][k];
    float4 wa = *(const float4*)&Mt[k][c0];
    float4 wb = *(const float4*)&Mt[k][c0+4];
    acc[0]+=z*wa.x; acc[1]+=z*wa.y; acc[2]+=z*wa.z; acc[3]+=z*wa.w;
    acc[4]+=z*wb.x; acc[5]+=z*wb.y; acc[6]+=z*wb.z; acc[7]+=z*wb.w;
  }
  float4 ba = *(const float4*)&lin_b[c0];
  float4 bb = *(const float4*)&lin_b[c0+4];
  float4 r0, r1;
  r0.x = fmaxf(acc[0]+ba.x,0.f); r0.y = fmaxf(acc[1]+ba.y,0.f);
  r0.z = fmaxf(acc[2]+ba.z,0.f); r0.w = fmaxf(acc[3]+ba.w,0.f);
  r1.x = fmaxf(acc[4]+bb.x,0.f); r1.y = fmaxf(acc[5]+bb.y,0.f);
  r1.z = fmaxf(acc[6]+bb.z,0.f); r1.w = fmaxf(acc[7]+bb.w,0.f);
  float* dst = Z + (size_t)(n0+nl)*128 + c0;
  *(float4*)dst = r0; *(float4*)(dst+4) = r1;
}

// ---------------- gram img via MFMA (runtime chunk; 2-region partials) ---------
__launch_bounds__(256)
__global__ void gram_img_mfma_kernel(const float* __restrict__ X,
                                     const u16* __restrict__ xb,
                                     float* __restrict__ part,
                                     float* __restrict__ part2,
                                     float* __restrict__ psums,
                                     float* __restrict__ psums2,
                                     int chunk, int ntiles) {
  __shared__ __align__(16) u16 tile[128*64];   // [c][px64] bf16, XOR-swizzled
  const int b = blockIdx.x, t = threadIdx.x;
  const int px0 = b * chunk;
  const int wv = t >> 6, l = t & 63;
  const int i0 = (wv >> 1) * 64, j0 = (wv & 1) * 64;
  const int row16 = l & 15, kq = l >> 4;
  const int pg = t & 15;
  const int g0 = t >> 4;
  const int cb16 = t >> 1, hb16 = t & 1;
  float csum[8];
#pragma unroll
  for (int q = 0; q < 8; ++q) csum[q] = 0.f;
  f32x4 acc[4][4];
#pragma unroll
  for (int a = 0; a < 4; ++a)
#pragma unroll
    for (int q = 0; q < 4; ++q) acc[a][q] = (f32x4){0.f,0.f,0.f,0.f};

  if (xb) {
    uint4 vcur[4];
#pragma unroll
    for (int gi = 0; gi < 4; ++gi) {
      int g = hb16*4 + gi;
      vcur[gi] = *(const uint4*)(xb + (size_t)cb16*HWSZ + px0 + g*8);
    }
#pragma unroll 1
    for (int ti = 0; ti < ntiles; ++ti) {
      __syncthreads();   // previous MFMA done reading tile
#pragma unroll
      for (int gi = 0; gi < 4; ++gi) {
        int g = hb16*4 + gi;
        *(uint4*)((char*)tile + cb16*128 + ((g*16) ^ ((cb16 & 7) << 4))) = vcur[gi];
        const u16* p16 = (const u16*)&vcur[gi];
#pragma unroll
        for (int j = 0; j < 8; ++j) csum[0] += from_bf16(p16[j]);
      }
      uint4 vnext[4];
#pragma unroll
      for (int gi = 0; gi < 4; ++gi) {
        int g = hb16*4 + gi;
        int plg = (ti+1)*64 + g*8;
        if (ti < ntiles-1 && plg < chunk)
          vnext[gi] = *(const uint4*)(xb + (size_t)cb16*HWSZ + px0 + plg);
        else
          vnext[gi] = make_uint4(0u,0u,0u,0u);
      }
      __syncthreads();
#pragma unroll
      for (int f = 0; f < 2; ++f) {
        bf16x8 Af[4], Bf[4];
#pragma unroll
        for (int mt = 0; mt < 4; ++mt) {
          int c = i0 + mt*16 + row16;
          Af[mt] = *(const bf16x8*)((char*)tile + c*128 + ((f*64 + kq*16) ^ ((c & 7) << 4)));
        }
#pragma unroll
        for (int nt = 0; nt < 4; ++nt) {
          int c = j0 + nt*16 + row16;
          Bf[nt] = *(const bf16x8*)((char*)tile + c*128 + ((f*64 + kq*16) ^ ((c & 7) << 4)));
        }
#pragma unroll
        for (int mt = 0; mt < 4; ++mt)
#pragma unroll
          for (int nt = 0; nt < 4; ++nt)
            acc[mt][nt] = __builtin_amdgcn_mfma_f32_16x16x32_bf16(Af[mt], Bf[nt], acc[mt][nt], 0, 0, 0);
      }
#pragma unroll
      for (int gi = 0; gi < 4; ++gi) vcur[gi] = vnext[gi];
    }
  } else {
#pragma unroll 1
    for (int ti = 0; ti < ntiles; ++ti) {
      const int plg = ti*64 + pg*4;
      float4 v[8];
      if ((ti+1)*64 <= chunk) {
#pragma unroll
        for (int cc = 0; cc < 8; ++cc) {
          int c = g0 + cc*16;
          v[cc] = *(const float4*)(X + (size_t)c*HWSZ + px0 + plg);
        }
      } else {
#pragma unroll
        for (int cc = 0; cc < 8; ++cc) {
          int c = g0 + cc*16;
          const float* src = X + (size_t)c*HWSZ + px0;
#pragma unroll
          for (int j = 0; j < 4; ++j) {
            int p = plg + j;
            ((float*)&v[cc])[j] = (p < chunk) ? src[p] : 0.f;
          }
        }
      }
      __syncthreads();
#pragma unroll
      for (int cc = 0; cc < 8; ++cc) {
        int c = g0 + cc*16;
        csum[cc] += v[cc].x + v[cc].y + v[cc].z + v[cc].w;
        u32 w0 = pack_bf16(v[cc].x, v[cc].y);
        u32 w1 = pack_bf16(v[cc].z, v[cc].w);
        *(uint2*)((char*)tile + c*128 + ((pg*8) ^ ((c & 7) << 4))) = make_uint2(w0, w1);
      }
      __syncthreads();
#pragma unroll
      for (int f = 0; f < 2; ++f) {
        bf16x8 Af[4], Bf[4];
#pragma unroll
        for (int mt = 0; mt < 4; ++mt) {
          int c = i0 + mt*16 + row16;
          Af[mt] = *(const bf16x8*)((char*)tile + c*128 + ((f*64 + kq*16) ^ ((c & 7) << 4)));
        }
#pragma unroll
        for (int nt = 0; nt < 4; ++nt) {
          int c = j0 + nt*16 + row16;
          Bf[nt] = *(const bf16x8*)((char*)tile + c*128 + ((f*64 + kq*16) ^ ((c & 7) << 4)));
        }
#pragma unroll
        for (int mt = 0; mt < 4; ++mt)
#pragma unroll
          for (int nt = 0; nt < 4; ++nt)
            acc[mt][nt] = __builtin_amdgcn_mfma_f32_16x16x32_bf16(Af[mt], Bf[nt], acc[mt][nt], 0, 0, 0);
      }
      __syncthreads();
    }
  }
  float* pd = (b < 256) ? (psums + (size_t)b*128) : (psums2 + (size_t)(b-256)*128);
  if (xb) {
    float s = csum[0];
    s += __shfl_xor(s, 1, 64);
    if ((t & 1) == 0) pd[cb16] = s;
  } else {
#pragma unroll
    for (int cc = 0; cc < 8; ++cc) {
      float s = csum[cc];
      s += __shfl_xor(s, 1, 64);
      s += __shfl_xor(s, 2, 64);
      s += __shfl_xor(s, 4, 64);
      s += __shfl_xor(s, 8, 64);
      if (pg == 0) pd[g0 + cc*16] = s;
    }
  }
  float* dst = (b < 256) ? (part + (size_t)b*16384) : (part2 + (size_t)(b-256)*16384);
#pragma unroll
  for (int mt = 0; mt < 4; ++mt)
#pragma unroll
    for (int nt = 0; nt < 4; ++nt) {
#pragma unroll
      for (int r = 0; r < 4; ++r) {
        int i = i0 + mt*16 + kq*4 + r;
        int j = j0 + nt*16 + row16;
        dst[i*128 + j] = acc[mt][nt][r];
      }
    }
}

// ---------------- gram pcd (fp32) + fused channel partial sums -----------------
__launch_bounds__(256)
__global__ void gram_pcd_kernel(const float* __restrict__ Z, float* __restrict__ part,
                                float* __restrict__ psums_p) {
  __shared__ __align__(16) float zt[64][132];
  __shared__ float ps4[4][32][4];
  const int b = blockIdx.x, t = threadIdx.x;
  const int n0 = b * CHUNK_P;
  const int i0 = (t >> 4) * 8, j0 = (t & 15) * 8;
  float acc[8][8];
#pragma unroll
  for (int a = 0; a < 8; a++)
#pragma unroll
    for (int q = 0; q < 8; q++) acc[a][q] = 0.f;
  float fsum[4] = {0.f, 0.f, 0.f, 0.f};
  for (int tile = 0; tile < 6; tile++) {
    __syncthreads();
#pragma unroll
    for (int i = 0; i < 8; i++) {
      int idx = t + i*256; int r = idx >> 5; int c4 = (idx & 31)*4;
      int lrow = tile*64 + r;
      int n = n0 + lrow;
      float4 v = {0.f,0.f,0.f,0.f};
      if (lrow < CHUNK_P && n < NPC) v = *(const float4*)&Z[(size_t)n*128 + c4];
      *(float4*)&zt[r][c4] = v;
      fsum[0] += v.x; fsum[1] += v.y; fsum[2] += v.z; fsum[3] += v.w;
    }
    __syncthreads();
#pragma unroll 4
    for (int n = 0; n < 64; n++) {
      float4 a0 = *(const float4*)&zt[n][i0];
      float4 a1 = *(const float4*)&zt[n][i0+4];
      float4 b0 = *(const float4*)&zt[n][j0];
      float4 b1 = *(const float4*)&zt[n][j0+4];
      float av[8] = {a0.x,a0.y,a0.z,a0.w,a1.x,a1.y,a1.z,a1.w};
      float bv[8] = {b0.x,b0.y,b0.z,b0.w,b1.x,b1.y,b1.z,b1.w};
#pragma unroll
      for (int a = 0; a < 8; a++)
#pragma unroll
        for (int q = 0; q < 8; q++) acc[a][q] += av[a]*bv[q];
    }
  }
  float* dst = part + (size_t)b*16384;
#pragma unroll
  for (int a = 0; a < 8; a++) {
    float4 w0v = {acc[a][0],acc[a][1],acc[a][2],acc[a][3]};
    float4 w1v = {acc[a][4],acc[a][5],acc[a][6],acc[a][7]};
    *(float4*)&dst[(i0+a)*128 + j0] = w0v;
    *(float4*)&dst[(i0+a)*128 + j0 + 4] = w1v;
  }
  const int wv2 = t >> 6;
#pragma unroll
  for (int j2 = 0; j2 < 4; ++j2) fsum[j2] += __shfl_down(fsum[j2], 32, 64);
  if ((t & 63) < 32) {
#pragma unroll
    for (int j2 = 0; j2 < 4; ++j2) ps4[wv2][t & 31][j2] = fsum[j2];
  }
  __syncthreads();
  if (t < 128) {
    float s = ps4[0][t>>2][t&3] + ps4[1][t>>2][t&3]
            + ps4[2][t>>2][t&3] + ps4[3][t>>2][t&3];
    psums_p[b*128 + t] = s;
  }
}

// ---------------- channel sums: 4 p-groups x 128 j, unroll-8 ILP ---------------
__launch_bounds__(512)
__global__ void sums_kernel(float* __restrict__ ws, int nparts_img) {
  const int b = blockIdx.x, t = threadIdx.x;
  const int g = t >> 7, j = t & 127;
  __shared__ float red[4][128];
  float a[8];
#pragma unroll
  for (int u = 0; u < 8; ++u) a[u] = 0.f;
  if (b == 0) {
    const int per = nparts_img >> 2;
    const int p0 = g * per;
    for (int k = 0; k < per; k += 8) {
#pragma unroll
      for (int u = 0; u < 8; ++u) {
        int p = p0 + k + u;
        const float* ps = (p < 256) ? (ws + OFF_PSUMS + (size_t)p*128)
                                    : (ws + OFF_PSUMS2 + (size_t)(p-256)*128);
        a[u] += ps[j];
      }
    }
  } else {
    const int p0 = g * 16;
    for (int k = 0; k < 16; k += 8) {
#pragma unroll
      for (int u = 0; u < 8; ++u)
        a[u] += ws[OFF_PSUMS_P + (size_t)(p0 + k + u)*128 + j];
    }
  }
  float s = ((a[0]+a[1])+(a[2]+a[3])) + ((a[4]+a[5])+(a[6]+a[7]));
  red[g][j] = s;
  __syncthreads();
  if (g == 0)
    ws[(b == 0 ? OFF_SUMS_IMG : OFF_SUMS_PCD) + j] =
        (red[0][j] + red[1][j]) + (red[2][j] + red[3][j]);
}

// ------- reduce partials -> cov: 4 p-groups x 128 j per row, unroll-8 ILP ------
__launch_bounds__(512)
__global__ void reduce_cov_kernel(float* __restrict__ ws, int nparts_img) {
  const int b = blockIdx.x, t = threadIdx.x;
  const int g = t >> 7, j = t & 127;
  const bool isimg = (b < 128);
  const int i = isimg ? b : b - 128;
  __shared__ float red[4][128];
  float a[8];
#pragma unroll
  for (int u = 0; u < 8; ++u) a[u] = 0.f;
  if (isimg) {
    const int per = nparts_img >> 2;
    const int p0 = g * per;
    for (int k = 0; k < per; k += 8) {
#pragma unroll
      for (int u = 0; u < 8; ++u) {
        int p = p0 + k + u;
        const float* part = (p < 256) ? (ws + OFF_PART_IMG + (size_t)p*16384)
                                      : (ws + OFF_PART2 + (size_t)(p-256)*16384);
        a[u] += part[i*128 + j];
      }
    }
  } else {
    const int p0 = g * 16;
    for (int k = 0; k < 16; k += 8) {
#pragma unroll
      for (int u = 0; u < 8; ++u)
        a[u] += ws[OFF_PART_PCD + (size_t)(p0 + k + u)*16384 + i*128 + j];
    }
  }
  float s = ((a[0]+a[1])+(a[2]+a[3])) + ((a[4]+a[5])+(a[6]+a[7]));
  red[g][j] = s;
  __syncthreads();
  if (g == 0) {
    float gsum = (red[0][j] + red[1][j]) + (red[2][j] + red[3][j]);
    const int so = isimg ? OFF_SUMS_IMG : OFF_SUMS_PCD;
    float Si = ws[so + i];
    float Sj = ws[so + j];
    float n = isimg ? (float)HWSZ : (float)NPC;
    float cov = (gsum - Si*Sj/n) / (n - 1.f);
    ws[(isimg ? OFF_COV_IMG : OFF_COV_PCD) + i*128 + j] = cov;
  }
}

// ---------------- blocked Gauss-Jordan inverse (panel=16) ----------------------
__launch_bounds__(256, 1)
__global__ void invert_kernel(float* __restrict__ ws) {
  __shared__ float A_[128*132];     // 67584 B
  __shared__ float Rb_[16*132];     // 8448 B
  __shared__ float prw[16];
  __shared__ float pcl[16];
  const int blk = blockIdx.x, t = threadIdx.x;
  const float* src = ws + (blk == 0 ? OFF_COV_IMG : OFF_COV_PCD);
  float* dst = ws + (blk == 0 ? OFF_INV_IMG : OFF_INV_PCD);
  for (int e = t; e < 16384; e += 256) {
    int i = e >> 7, j = e & 127;
    A_[i*132 + j] = src[e] + ((i == j) ? 1e-6f : 0.f);
  }
#pragma unroll 1
  for (int p = 0; p < 8; ++p) {
    const int k0 = p * 16;
    __syncthreads();
    if (t < 64) {
      const int r = t & 15, cg = t >> 4, cb = cg * 4;
      float4 d = *(const float4*)&A_[(k0 + r)*132 + k0 + cb];
#pragma unroll 1
      for (int k = 0; k < 16; ++k) {
        const int kg = k >> 2, km = k & 3;
        if (r == k) {
          prw[cb+0] = d.x; prw[cb+1] = d.y; prw[cb+2] = d.z; prw[cb+3] = d.w;
        }
        if (cg == kg) {
          float el = (km==0) ? d.x : (km==1) ? d.y : (km==2) ? d.z : d.w;
          pcl[r] = el;
        }
        __builtin_amdgcn_wave_barrier();
        float ip = 1.f / pcl[k];
        float f  = pcl[r];
        float p0 = prw[cb+0], p1 = prw[cb+1], p2 = prw[cb+2], p3 = prw[cb+3];
        __builtin_amdgcn_wave_barrier();
        if (r == k) {
          d.x *= ip; d.y *= ip; d.z *= ip; d.w *= ip;
          if (cg == kg) { if (km==0) d.x=ip; else if (km==1) d.y=ip; else if (km==2) d.z=ip; else d.w=ip; }
        } else {
          float g = f * ip;
          d.x -= g*p0; d.y -= g*p1; d.z -= g*p2; d.w -= g*p3;
          if (cg == kg) { if (km==0) d.x=-g; else if (km==1) d.y=-g; else if (km==2) d.z=-g; else d.w=-g; }
        }
        __builtin_amdgcn_wave_barrier();
      }
      *(float4*)&Rb_[r*132 + k0 + cb] = d;
    }
    __syncthreads();
    {
      const int r = t & 15, ch = t >> 4;
      if ((ch >> 1) != p) {
        const int j0 = ch * 8;
        float4 dv0 = *(const float4*)&Rb_[r*132 + k0];
        float4 dv1 = *(const float4*)&Rb_[r*132 + k0 + 4];
        float4 dv2 = *(const float4*)&Rb_[r*132 + k0 + 8];
        float4 dv3 = *(const float4*)&Rb_[r*132 + k0 + 12];
        float dv[16] = {dv0.x,dv0.y,dv0.z,dv0.w, dv1.x,dv1.y,dv1.z,dv1.w,
                        dv2.x,dv2.y,dv2.z,dv2.w, dv3.x,dv3.y,dv3.z,dv3.w};
        float4 a0 = {0,0,0,0}, a1 = {0,0,0,0};
#pragma unroll
        for (int s = 0; s < 16; ++s) {
          float4 r0v = *(const float4*)&A_[(k0+s)*132 + j0];
          float4 r1v = *(const float4*)&A_[(k0+s)*132 + j0 + 4];
          float w = dv[s];
          a0.x += w*r0v.x; a0.y += w*r0v.y; a0.z += w*r0v.z; a0.w += w*r0v.w;
          a1.x += w*r1v.x; a1.y += w*r1v.y; a1.z += w*r1v.z; a1.w += w*r1v.w;
        }
        *(float4*)&Rb_[r*132 + j0] = a0;
        *(float4*)&Rb_[r*132 + j0 + 4] = a1;
      }
    }
    __syncthreads();
    {
      const int tr = t >> 4, tc = t & 15;
      const int r0 = tr * 8, c0 = tc * 8;
      const bool pivrow = (tr >> 1) == p;
      const bool pivcol = (tc >> 1) == p;
      float4 acc[8][2];
      float4 F4[8][4];
      if (pivrow) {
#pragma unroll
        for (int i = 0; i < 8; ++i) {
          acc[i][0] = *(const float4*)&Rb_[(r0 + i - k0)*132 + c0];
          acc[i][1] = *(const float4*)&Rb_[(r0 + i - k0)*132 + c0 + 4];
        }
      } else {
#pragma unroll
        for (int i = 0; i < 8; ++i) {
          F4[i][0] = *(const float4*)&A_[(r0+i)*132 + k0];
          F4[i][1] = *(const float4*)&A_[(r0+i)*132 + k0 + 4];
          F4[i][2] = *(const float4*)&A_[(r0+i)*132 + k0 + 8];
          F4[i][3] = *(const float4*)&A_[(r0+i)*132 + k0 + 12];
        }
        if (pivcol) {
#pragma unroll
          for (int i = 0; i < 8; ++i) {
            acc[i][0] = make_float4(0.f,0.f,0.f,0.f);
            acc[i][1] = make_float4(0.f,0.f,0.f,0.f);
          }
        } else {
#pragma unroll
          for (int i = 0; i < 8; ++i) {
            acc[i][0] = *(const float4*)&A_[(r0+i)*132 + c0];
            acc[i][1] = *(const float4*)&A_[(r0+i)*132 + c0 + 4];
          }
        }
      }
      __syncthreads();
      if (!pivrow) {
#pragma unroll
        for (int s = 0; s < 16; ++s) {
          float4 rb0 = *(const float4*)&Rb_[s*132 + c0];
          float4 rb1 = *(const float4*)&Rb_[s*132 + c0 + 4];
#pragma unroll
          for (int i = 0; i < 8; ++i) {
            float fs = (s&3)==0 ? F4[i][s>>2].x : (s&3)==1 ? F4[i][s>>2].y
                     : (s&3)==2 ? F4[i][s>>2].z : F4[i][s>>2].w;
            acc[i][0] = f4_fnma(acc[i][0], fs, rb0);
            acc[i][1] = f4_fnma(acc[i][1], fs, rb1);
          }
        }
      }
#pragma unroll
      for (int i = 0; i < 8; ++i) {
        *(float4*)&A_[(r0+i)*132 + c0]     = acc[i][0];
        *(float4*)&A_[(r0+i)*132 + c0 + 4] = acc[i][1];
      }
    }
  }
  __syncthreads();
  for (int e = t; e < 16384; e += 256)
    dst[e] = A_[(e >> 7)*132 + (e & 127)];
}

// ---------------- attention rows -> mix matrices (img: bf16 frags, pcd: MT) ----
__launch_bounds__(128)
__global__ void attn_kernel(float* __restrict__ ws) {
  const int b = blockIdx.x, j = threadIdx.x;
  const bool isimg = (b < 128);
  const int i = isimg ? b : b - 128;
  const float* rowA = ws + (isimg ? OFF_COV_PCD : OFF_COV_IMG) + i*128;
  const float* matA = ws + (isimg ? OFF_INV_IMG : OFF_INV_PCD);
  const float* rowB = ws + (isimg ? OFF_COV_IMG : OFF_COV_PCD) + i*128;
  const float* matB = ws + (isimg ? OFF_COV_IMG : OFF_COV_PCD);
  __shared__ float rA[128], rB[128], red[128];
  rA[j] = rowA[j]; rB[j] = rowB[j];
  __syncthreads();
  float dA = 0.f, dB = 0.f;
#pragma unroll 8
  for (int k = 0; k < 128; ++k) {
    dA += rA[k] * matA[k*128 + j];
    dB += rB[k] * matB[k*128 + j];
  }
  dA *= 0.0078125f; dB *= 0.0078125f;
  red[j] = dA; __syncthreads();
  for (int s2 = 64; s2 > 0; s2 >>= 1) { if (j < s2) red[j] = fmaxf(red[j], red[j+s2]); __syncthreads(); }
  float mA = red[0]; __syncthreads();
  float eA = expf(dA - mA);
  red[j] = eA; __syncthreads();
  for (int s2 = 64; s2 > 0; s2 >>= 1) { if (j < s2) red[j] += red[j+s2]; __syncthreads(); }
  float sA = red[0]; __syncthreads();
  red[j] = dB; __syncthreads();
  for (int s2 = 64; s2 > 0; s2 >>= 1) { if (j < s2) red[j] = fmaxf(red[j], red[j+s2]); __syncthreads(); }
  float mB = red[0]; __syncthreads();
  float eB = expf(dB - mB);
  red[j] = eB; __syncthreads();
  for (int s2 = 64; s2 > 0; s2 >>= 1) { if (j < s2) red[j] += red[j+s2]; __syncthreads(); }
  float sB = red[0]; __syncthreads();
  float m = 0.1f * (eA/sA + eB/sB);   // M[i][j]
  if (isimg) {
    int f = j >> 5, ob = i >> 4, l = ((j >> 3) & 3)*16 + (i & 15), jj = j & 7;
    ((u16*)(ws + OFF_MB))[(f*8 + ob)*512 + l*8 + jj] = to_bf16(m);
  } else {
    ws[OFF_MT_PCD + j*128 + i] = m;   // transposed: MT[k][c]
  }
}

// ---------------- img final via MFMA, two-pass transpose (4 blocks/CU) ---------
__launch_bounds__(256, 4)
__global__ void img_final_mfma_kernel(const float* __restrict__ img_in,
                                      const float* __restrict__ ws,
                                      const u16* __restrict__ xb,
                                      float* __restrict__ io) {
  __shared__ __align__(16) char smem[34816];   // max(bt 32768, ts 34816)
  u16* bt = (u16*)smem;          // [128px][128c] bf16, XOR-swizzled
  float* ts = (float*)smem;      // [128c][68px]
  const int blk = blockIdx.x, t = threadIdx.x;
  const int px0 = blk * 128;
  const int pxg = (t & 31) * 4;
  const int cp0 = t >> 5;
  if (xb) {
#pragma unroll
    for (int cc = 0; cc < 8; ++cc) {
      int cpair = cp0 + cc*8;
      const u16* s0 = xb + (size_t)(2*cpair)*HWSZ + px0 + pxg;
      uint2 ua = *(const uint2*)s0;
      uint2 ub = *(const uint2*)(s0 + HWSZ);
      u32 w[4];
      w[0] = (ua.x & 0xFFFFu) | ((ub.x & 0xFFFFu) << 16);
      w[1] = (ua.x >> 16)     | (ub.x & 0xFFFF0000u);
      w[2] = (ua.y & 0xFFFFu) | ((ub.y & 0xFFFFu) << 16);
      w[3] = (ua.y >> 16)     | (ub.y & 0xFFFF0000u);
#pragma unroll
      for (int j = 0; j < 4; ++j) {
        int pxl = pxg + j;
        *(u32*)((char*)bt + pxl*256 + ((cpair*4) ^ ((pxl & 7) << 4))) = w[j];
      }
    }
  } else {
#pragma unroll
    for (int cc = 0; cc < 8; ++cc) {
      int cpair = cp0 + cc*8;
      const float* s0 = io + (size_t)(2*cpair)*HWSZ + px0 + pxg;
      float4 a = *(const float4*)s0;
      float4 b4 = *(const float4*)(s0 + HWSZ);
#pragma unroll
      for (int j = 0; j < 4; ++j) {
        int pxl = pxg + j;
        *(u32*)((char*)bt + pxl*256 + ((cpair*4) ^ ((pxl & 7) << 4))) =
            pack_bf16(((const float*)&a)[j], ((const float*)&b4)[j]);
      }
    }
  }
  __syncthreads();
  const int wv = t >> 6, l = t & 63;
  const int i0 = (wv >> 1) * 64, j0 = (wv & 1) * 64;
  const int row16 = l & 15, kq = l >> 4;
  const u16* Mbf = (const u16*)(ws + OFF_MB);
  f32x4 acc[4][4];
#pragma unroll
  for (int a = 0; a < 4; ++a)
#pragma unroll
    for (int q = 0; q < 4; ++q) acc[a][q] = (f32x4){0.f,0.f,0.f,0.f};
#pragma unroll
  for (int f = 0; f < 4; ++f) {
    bf16x8 Bf[4], Am[4];
#pragma unroll
    for (int nt = 0; nt < 4; ++nt) {
      int pxl = j0 + nt*16 + row16;
      Bf[nt] = *(const bf16x8*)((char*)bt + pxl*256 + ((f*64 + kq*16) ^ ((pxl & 7) << 4)));
    }
#pragma unroll
    for (int mt = 0; mt < 4; ++mt) {
      int ob = (wv >> 1) * 4 + mt;
      Am[mt] = *(const bf16x8*)(Mbf + (f*8 + ob)*512 + l*8);
    }
#pragma unroll
    for (int mt = 0; mt < 4; ++mt)
#pragma unroll
      for (int nt = 0; nt < 4; ++nt)
        acc[mt][nt] = __builtin_amdgcn_mfma_f32_16x16x32_bf16(Am[mt], Bf[nt], acc[mt][nt], 0, 0, 0);
  }
#pragma unroll 1
  for (int half = 0; half < 2; ++half) {
    __syncthreads();
    if ((wv & 1) == half) {
#pragma unroll
      for (int mt = 0; mt < 4; ++mt)
#pragma unroll
        for (int nt = 0; nt < 4; ++nt) {
          int lpx = nt*16 + row16;
#pragma unroll
          for (int r = 0; r < 4; ++r) {
            int c = i0 + mt*16 + kq*4 + r;
            ts[c*68 + lpx] = acc[mt][nt][r];
          }
        }
    }
    __syncthreads();
    const int cq = t >> 2, p4 = (t & 3) * 4;
#pragma unroll
    for (int cp = 0; cp < 2; ++cp) {
      int c = cp*64 + cq;
#pragma unroll
      for (int j = 0; j < 4; ++j) {
        int lpx = p4 + j*16;
        float4 v = *(const float4*)&ts[c*68 + lpx];
        size_t off = (size_t)c*HWSZ + px0 + half*64 + lpx;
        float4 o = *(const float4*)&img_in[off];
        float4 r;
        r.x = v.x + 0.8f*o.x; r.y = v.y + 0.8f*o.y;
        r.z = v.z + 0.8f*o.z; r.w = v.w + 0.8f*o.w;
        *(float4*)&io[off] = r;
      }
    }
  }
}

// ---------------- pcd final: Z = Z @ M_pcd^T + 0.8*pcd (in place) --------------
__launch_bounds__(256)
__global__ void pcd_final_kernel(const float* __restrict__ pcd_in,
                                 const float* __restrict__ ws,
                                 float* __restrict__ Z) {
  __shared__ __align__(16) float Mt[128][132];
  __shared__ __align__(16) float zs[16][132];
  const int b = blockIdx.x, t = threadIdx.x;
  const int n0 = b * 16;
#pragma unroll
  for (int i = 0; i < 16; i++) {
    int idx = t + i*256; int r = idx >> 5; int c4 = (idx & 31)*4;
    *(float4*)&Mt[r][c4] = *(const float4*)&ws[OFF_MT_PCD + r*128 + c4];
  }
#pragma unroll
  for (int i = 0; i < 2; i++) {
    int idx = t + i*256; int r = idx >> 5; int c4 = (idx & 31)*4;
    *(float4*)&zs[r][c4] = *(const float4*)&Z[(size_t)(n0+r)*128 + c4];
  }
  __syncthreads();
  const int nl = t & 15;
  const int c0 = (t >> 4) * 8;
  float acc[8];
#pragma unroll
  for (int q = 0; q < 8; q++) acc[q] = 0.f;
#pragma unroll 8
  for (int k = 0; k < 128; k++) {
    float z = zs[nl][k];
    float4 wa = *(const float4*)&Mt[k][c0];
    float4 wb = *(const float4*)&Mt[k][c0+4];
    acc[0]+=z*wa.x; acc[1]+=z*wa.y; acc[2]+=z*wa.z; acc[3]+=z*wa.w;
    acc[4]+=z*wb.x; acc[5]+=z*wb.y; acc[6]+=z*wb.z; acc[7]+=z*wb.w;
  }
  size_t off = (size_t)(n0+nl)*128 + c0;
  float4 pa = *(const float4*)&pcd_in[off];
  float4 pb = *(const float4*)&pcd_in[off+4];
  float4 r0, r1;
  r0.x = acc[0] + 0.8f*pa.x; r0.y = acc[1] + 0.8f*pa.y;
  r0.z = acc[2] + 0.8f*pa.z; r0.w = acc[3] + 0.8f*pa.w;
  r1.x = acc[4] + 0.8f*pb.x; r1.y = acc[5] + 0.8f*pb.y;
  r1.z = acc[6] + 0.8f*pb.z; r1.w = acc[7] + 0.8f*pb.w;
  *(float4*)&Z[off] = r0; *(float4*)&Z[off+4] = r1;
}

extern "C" void kernel_launch(void* const* d_in, const int* in_sizes, int n_in,
                              void* d_out, int out_size, void* d_ws, size_t ws_size,
                              hipStream_t stream) {
  (void)in_sizes; (void)n_in; (void)out_size;
  const float* img_in = (const float*)d_in[0];
  const float* pcd_in = (const float*)d_in[1];
  const float* conv_w = (const float*)d_in[2];
  const float* conv_b = (const float*)d_in[3];
  const float* gamma  = (const float*)d_in[4];
  const float* beta   = (const float*)d_in[5];
  const float* mean   = (const float*)d_in[6];
  const float* var    = (const float*)d_in[7];
  const float* lin_w  = (const float*)d_in[8];
  const float* lin_b  = (const float*)d_in[9];
  float* out = (float*)d_out;
  float* X = out;            // [128][307200] conv output (fp32 path)
  float* Z = out + IMG_SZ;   // [22432][128] linear output, transformed in place
  float* ws = (float*)d_ws;
  const int big  = (ws_size >= (size_t)WS_NEED_FLOATS * 4) ? 1 : 0;
  const int big2 = (ws_size >= (size_t)WS_NEED2_FLOATS * 4) ? 1 : 0;
  u16* Xb = big2 ? (u16*)(ws + OFF_XB) : (u16*)nullptr;

  hipLaunchKernelGGL(prep_kernel, dim3(64), dim3(256), 0, stream,
                     conv_w, conv_b, gamma, beta, mean, var, lin_w, ws, big);
  if (big) {
    u16* Timg = (u16*)(ws + OFF_TIMG_F);
    u16* Wf = (u16*)(ws + OFF_WB);
    hipLaunchKernelGGL(timg_kernel, dim3(4941), dim3(256), 0, stream, img_in, Timg);
    hipLaunchKernelGGL(conv_mfma8_kernel, dim3(1200), dim3(256), 0, stream, Timg, Wf, ws, X, Xb);
  } else {
    hipLaunchKernelGGL(conv_kernel, dim3(4800), dim3(256), 0, stream, img_in, ws, X);
  }
  hipLaunchKernelGGL(linear_kernel, dim3(NPC/16), dim3(256), 0, stream, pcd_in, ws, lin_b, Z);
  // gram_img: big path uses 512 chunks of 600 px (2 blocks/CU); partials for
  // blocks >=256 alias the dead Timg region (rewritten by timg each replay).
  {
    int nbi    = big ? 512 : 256;
    int chunk  = big ? 600 : 1200;
    int ntiles = big ? 10  : 19;
    hipLaunchKernelGGL(gram_img_mfma_kernel, dim3(nbi), dim3(256), 0, stream,
                       X, Xb, ws + OFF_PART_IMG, ws + OFF_PART2,
                       ws + OFF_PSUMS, ws + OFF_PSUMS2, chunk, ntiles);
    hipLaunchKernelGGL(gram_pcd_kernel, dim3(NBP), dim3(256), 0, stream,
                       Z, ws + OFF_PART_PCD, ws + OFF_PSUMS_P);
    hipLaunchKernelGGL(sums_kernel, dim3(2), dim3(512), 0, stream, ws, nbi);
    hipLaunchKernelGGL(reduce_cov_kernel, dim3(256), dim3(512), 0, stream, ws, nbi);
  }
  hipLaunchKernelGGL(invert_kernel, dim3(2), dim3(256), 0, stream, ws);
  hipLaunchKernelGGL(attn_kernel, dim3(256), dim3(128), 0, stream, ws);
  hipLaunchKernelGGL(img_final_mfma_kernel, dim3(HWSZ/128), dim3(256), 0, stream,
                     img_in, ws, Xb, X);
  hipLaunchKernelGGL(pcd_final_kernel, dim3(NPC/16), dim3(256), 0, stream, pcd_in, ws, Z);
}

// Round 22
// 462.921 us; speedup vs baseline: 1.5964x; 1.0381x over previous
//
#include <hip/hip_runtime.h>
#include <math.h>

#define HH 480
#define WW 640
#define HWSZ (HH*WW)        // 307200
#define NPC 22432
#define IMG_SZ (128*HWSZ)   // 39321600
#define NBP 64              // gram pcd partial blocks
#define CHUNK_P 351         // 64*351 = 22464 >= 22432

typedef unsigned short u16;
typedef unsigned int u32;
typedef __attribute__((ext_vector_type(8))) short bf16x8;
typedef __attribute__((ext_vector_type(4))) float f32x4;

// ws float offsets
#define OFF_SUMS_IMG 0
#define OFF_SUMS_PCD 128
#define OFF_BIAS2    256
#define OFF_COV_IMG  512
#define OFF_COV_PCD  16896
#define OFF_INV_IMG  33280
#define OFF_INV_PCD  49664
#define OFF_MT_IMG   66048
#define OFF_MT_PCD   82432
#define OFF_LWT      98816
#define OFF_PSUMS    115200     // 256*128 = 32768
#define OFF_MB       147968     // M_img bf16 fragments: 16384 u16 = 4096 floats
#define OFF_WT       152064     // 128*9*128 fp32 (fallback conv) = 147456
#define OFF_PSUMS_P  OFF_WT     // pcd psums (64*128) reuse WT region (dead after conv)
#define OFF_PART_IMG 299520     // 256*16384 = 4194304
#define OFF_PART_PCD 4493824    // NBP*16384 = 1048576
#define OFF_WB       5542400    // 9*128*128 bf16 = 73728 floats (fragment layout)
#define OFF_TIMG_F   5616128    // 4 planes x 309444 px x 32c bf16 = 19804416 floats
#define OFF_PART2    OFF_TIMG_F             // 256*16384 floats (aliases dead Timg)
#define OFF_PSUMS2   (OFF_TIMG_F + 4194304) // 256*128 floats (aliases dead Timg)
#define TIMG_PAD_W 642
#define TIMG_PX (482*642)       // 309444
#define TIMG_PLANE (TIMG_PX*32) // u16 per ci-quarter plane
#define WS_NEED_FLOATS 25420544
#define OFF_XB       25420544   // X bf16 [128][307200] u16 = 19660800 floats
#define WS_NEED2_FLOATS 45081344

__device__ inline u32 pack_bf16(float a, float b) {
  u32 ua = __float_as_uint(a), ub = __float_as_uint(b);
  ua += 0x7FFFu + ((ua >> 16) & 1u);
  ub += 0x7FFFu + ((ub >> 16) & 1u);
  return (ua >> 16) | (ub & 0xFFFF0000u);
}
__device__ inline u16 to_bf16(float v) {
  u32 u = __float_as_uint(v); u += 0x7FFFu + ((u >> 16) & 1u);
  return (u16)(u >> 16);
}
__device__ inline float from_bf16(u16 v) {
  return __uint_as_float(((u32)v) << 16);
}
__device__ inline float4 f4_fnma(float4 v, float f, float4 p) {
  return make_float4(v.x - f*p.x, v.y - f*p.y, v.z - f*p.z, v.w - f*p.w);
}
__device__ inline void gload_lds16(const void* g, void* l) {
  __builtin_amdgcn_global_load_lds(
      (const __attribute__((address_space(1))) void*)(g),
      (__attribute__((address_space(3))) void*)(l), 16, 0, 0);
}

// ---------------- prep: fold BN into conv weights (fragment layout) ------------
__global__ void prep_kernel(const float* __restrict__ conv_w, const float* __restrict__ conv_b,
                            const float* __restrict__ gamma, const float* __restrict__ beta,
                            const float* __restrict__ mean, const float* __restrict__ var,
                            const float* __restrict__ lin_w, float* __restrict__ ws, int big) {
  int tid = blockIdx.x * blockDim.x + threadIdx.x;
  int nth = gridDim.x * blockDim.x;
  for (int oc = tid; oc < 128; oc += nth) {
    float s = gamma[oc] / sqrtf(var[oc] + 1e-5f);
    ws[OFF_BIAS2 + oc] = (conv_b[oc] - mean[oc]) * s + beta[oc];
  }
  if (big) {
    u16* Wf = (u16*)(ws + OFF_WB);
    for (int e = tid; e < 9*128*128; e += nth) {
      int j = e & 7, l = (e >> 3) & 63, ob = (e >> 9) & 7;
      int ci32 = (e >> 12) & 3, tap = e >> 14;
      int oc = ob*16 + (l & 15);
      int ci = ci32*32 + ((l >> 4) & 3)*8 + j;
      float s = gamma[oc] / sqrtf(var[oc] + 1e-5f);
      Wf[e] = to_bf16(conv_w[(oc*128 + ci)*9 + tap] * s);
    }
  } else {
    for (int e = tid; e < 128*9*128; e += nth) {
      int oc = e & 127; int k = (e >> 7) % 9; int ci = e / 1152;
      float s = gamma[oc] / sqrtf(var[oc] + 1e-5f);
      ws[OFF_WT + e] = conv_w[(oc*128 + ci)*9 + k] * s;
    }
  }
  for (int e = tid; e < 128*128; e += nth) {
    int c2 = e & 127; int k = e >> 7;
    ws[OFF_LWT + e] = lin_w[c2*128 + k];
  }
}

// ---- img fp32 -> Timg bf16, 4 ci-quarter planes, units XOR-permuted by (w>>2)&3
__launch_bounds__(256)
__global__ void timg_kernel(const float* __restrict__ img, u16* __restrict__ Timg) {
  __shared__ float xt[64][133];
  const int b = blockIdx.x;
  const int t = threadIdx.x;
  if (b >= 4800) {
    int tid = (b - 4800) * 256 + t;
    if (tid < (642*2 + 480*2) * 16) {
      int px = tid >> 4, u = tid & 15;
      int q = u >> 2, j = u & 3;
      int addr;
      if (px < 642) addr = px;
      else if (px < 1284) addr = 481*642 + (px - 642);
      else if (px < 1764) addr = (px - 1284 + 1) * 642;
      else addr = (px - 1764 + 1) * 642 + 641;
      ((uint4*)Timg)[(size_t)q*(TIMG_PX*4) + (size_t)addr*4 + j] = make_uint4(0u,0u,0u,0u);
    }
    return;
  }
  const int h = b / 10, w0 = (b % 10) * 64;
  const int wq = t & 15, cg = t >> 4;
#pragma unroll
  for (int i = 0; i < 8; ++i) {
    int ci = cg + i*16;
    float4 v = *(const float4*)&img[(size_t)ci*HWSZ + h*WW + w0 + wq*4];
    xt[wq*4+0][ci] = v.x; xt[wq*4+1][ci] = v.y;
    xt[wq*4+2][ci] = v.z; xt[wq*4+3][ci] = v.w;
  }
  __syncthreads();
  const int wp = t >> 2, q = t & 3, c0 = q * 32;
  u32 out[16];
#pragma unroll
  for (int j = 0; j < 16; ++j) {
    float a = xt[wp][c0 + 2*j], bb = xt[wp][c0 + 2*j + 1];
    out[j] = pack_bf16(a, bb);
  }
  uint4 ud[4];
#pragma unroll
  for (int u = 0; u < 4; ++u)
    ud[u] = make_uint4(out[u*4], out[u*4+1], out[u*4+2], out[u*4+3]);
  u16* dst = Timg + (size_t)q*TIMG_PLANE
           + ((size_t)(h+1)*TIMG_PAD_W + (w0 + 1 + wp)) * 32;
  const int key = ((1 + wp) >> 2) & 3;
  uint4* d4 = (uint4*)dst;
  switch (key) {
    case 0: d4[0]=ud[0]; d4[1]=ud[1]; d4[2]=ud[2]; d4[3]=ud[3]; break;
    case 1: d4[0]=ud[1]; d4[1]=ud[0]; d4[2]=ud[3]; d4[3]=ud[2]; break;
    case 2: d4[0]=ud[2]; d4[1]=ud[3]; d4[2]=ud[0]; d4[3]=ud[1]; break;
    default: d4[0]=ud[3]; d4[1]=ud[2]; d4[2]=ud[1]; d4[3]=ud[0]; break;
  }
}

// ---- conv v13: r16 schedule, half-width tile (32 cols) -> 2400 blocks, 32KB LDS
#define REG_ROWS 6
#define REG_COLS 34
#define REG_PX (REG_ROWS*REG_COLS)   // 204
#define STAGE_E (REG_PX*4)           // 816
#define BUF_E 1024                    // entries per buffer incl. scrap
__launch_bounds__(256, 2)
__global__ void conv_mfma11_kernel(const u16* __restrict__ Timg,
                                   const u16* __restrict__ Wf,
                                   const float* __restrict__ ws,
                                   float* __restrict__ X,
                                   u16* __restrict__ xb) {
  __shared__ __align__(16) u16 reg_lds[2][BUF_E * 8];   // 32768 B total
  const int b = blockIdx.x;
  const int h0 = (b / 20) * 4;
  const int w0 = (b % 20) * 32;
  const int t = threadIdx.x;
  const int wv = t >> 6, l = t & 63;
  const int n_lane = l & 15, k_lane = l >> 4;
  const int ocg = wv & 1;
  const int rowg = wv >> 1;

  f32x4 acc[4][4];
#pragma unroll
  for (int mt = 0; mt < 4; ++mt)
#pragma unroll
    for (int nt = 0; nt < 4; ++nt) acc[mt][nt] = (f32x4){0.f,0.f,0.f,0.f};

  // prologue: stage quarter 0 into buffer 0 (scrap-clamped tail)
  {
    const u16* plane = Timg;
#pragma unroll
    for (int i = 0; i < 4; ++i) {
      int e = t + i*256;
      int ec = (e < STAGE_E) ? e : (STAGE_E - 1);
      int px = ec >> 2, j = ec & 3;
      int r = px / REG_COLS, c = px - r * REG_COLS;
      const u16* src = plane + ((size_t)(h0 + r) * TIMG_PAD_W + (w0 + c)) * 32 + j*8;
      gload_lds16(src, reg_lds[0] + (size_t)e * 8);
    }
  }
  __syncthreads();   // drains vmcnt: buffer 0 ready

  int cur = 0;
#pragma unroll 1
  for (int qc = 0; qc < 4; ++qc) {
    // issue next quarter's loads into other buffer (hidden under MFMA below)
    if (qc < 3) {
      const u16* plane = Timg + (size_t)(qc+1) * TIMG_PLANE;
      u16* dstb = reg_lds[cur ^ 1];
#pragma unroll
      for (int i = 0; i < 4; ++i) {
        int e = t + i*256;
        int ec = (e < STAGE_E) ? e : (STAGE_E - 1);
        int px = ec >> 2, j = ec & 3;
        int r = px / REG_COLS, c = px - r * REG_COLS;
        const u16* src = plane + ((size_t)(h0 + r) * TIMG_PAD_W + (w0 + c)) * 32 + j*8;
        gload_lds16(src, dstb + (size_t)e * 8);
      }
    }
    const u16* curb = reg_lds[cur];
    const u16* wq = Wf + (qc*8 + ocg*4)*512 + l*8;
#pragma unroll 1
    for (int tap = 0; tap < 9; ++tap) {
      const int kh = (tap * 11) >> 5;
      const int kw = tap - kh * 3;
      const int cb = n_lane + kw;
      const int rb = rowg*2 + kh;
      const int uoff = (k_lane ^ ((cb >> 2) & 3)) << 4;
      const u16* wtap = wq + tap * 16384;
      bf16x8 Af[4], Bf[4];
#pragma unroll
      for (int mt = 0; mt < 4; ++mt)
        Af[mt] = *(const bf16x8*)(wtap + mt*512);
#pragma unroll
      for (int nt = 0; nt < 4; ++nt) {
        int px = (rb + (nt >> 1)) * REG_COLS + cb + (nt & 1) * 16;
        Bf[nt] = *(const bf16x8*)((const char*)curb + px * 64 + uoff);
      }
#pragma unroll
      for (int mt = 0; mt < 4; ++mt)
#pragma unroll
        for (int nt = 0; nt < 4; ++nt)
          acc[mt][nt] = __builtin_amdgcn_mfma_f32_16x16x32_bf16(Af[mt], Bf[nt], acc[mt][nt], 0, 0, 0);
    }
    __syncthreads();   // drain loads for next buffer + release current
    cur ^= 1;
  }
  const float* bias = ws + OFF_BIAS2;
  if (xb) {
#pragma unroll
    for (int mt = 0; mt < 4; ++mt) {
      f32x4 bv = *(const f32x4*)(bias + ocg*64 + mt*16 + k_lane*4);
#pragma unroll
      for (int nt = 0; nt < 4; ++nt) {
        int row = h0 + rowg*2 + (nt >> 1);
        int col = w0 + (nt & 1)*16 + n_lane;
#pragma unroll
        for (int rr = 0; rr < 4; ++rr) {
          int oc = ocg*64 + mt*16 + k_lane*4 + rr;
          float v = acc[mt][nt][rr] + bv[rr];
          xb[(size_t)oc * HWSZ + row*WW + col] = to_bf16(fmaxf(v, 0.f));
        }
      }
    }
  } else {
#pragma unroll
    for (int mt = 0; mt < 4; ++mt) {
      f32x4 bv = *(const f32x4*)(bias + ocg*64 + mt*16 + k_lane*4);
#pragma unroll
      for (int nt = 0; nt < 4; ++nt) {
        int row = h0 + rowg*2 + (nt >> 1);
        int col = w0 + (nt & 1)*16 + n_lane;
#pragma unroll
        for (int rr = 0; rr < 4; ++rr) {
          int oc = ocg*64 + mt*16 + k_lane*4 + rr;
          float v = acc[mt][nt][rr] + bv[rr];
          X[(size_t)oc * HWSZ + row*WW + col] = fmaxf(v, 0.f);
        }
      }
    }
  }
}

// ---------------- fp32 fallback conv -------------------------------------------
__launch_bounds__(256)
__global__ void conv_kernel(const float* __restrict__ img,
                            const float* __restrict__ ws,
                            float* __restrict__ outX) {
  __shared__ __align__(16) float xs[8][10][20];
  __shared__ __align__(16) float wsm[8][9][64];
  const int b = blockIdx.x;
  const int oc0 = (b & 1) * 64;
  const int sidx = b >> 1;
  const int h0 = (sidx / 40) * 8;
  const int w0 = (sidx % 40) * 16;
  const int t = threadIdx.x;
  const int oc_t = t & 15;
  const int px_t = t >> 4;
  const int ph = px_t >> 1;
  const int pw0 = (px_t & 1) * 8;
  float acc[4][8];
#pragma unroll
  for (int o = 0; o < 4; o++)
#pragma unroll
    for (int m = 0; m < 8; m++) acc[o][m] = 0.f;
  const float* wT = ws + OFF_WT;
  for (int ci0 = 0; ci0 < 128; ci0 += 8) {
    __syncthreads();
    for (int e = t; e < 1440; e += 256) {
      int ci = e / 180; int rem = e - ci*180; int r = rem / 18; int cc2 = rem - r*18;
      int gh = h0 + r - 1, gw = w0 + cc2 - 1;
      float v = 0.f;
      if ((unsigned)gh < (unsigned)HH && (unsigned)gw < (unsigned)WW)
        v = img[(ci0+ci)*HWSZ + gh*WW + gw];
      xs[ci][r][cc2] = v;
    }
    for (int e = t; e < 4608; e += 256) {
      int oc = e & 63; int k = (e >> 6) % 9; int ci = e / 576;
      wsm[ci][k][oc] = wT[((ci0+ci)*9 + k)*128 + oc0 + oc];
    }
    __syncthreads();
#pragma unroll
    for (int ci = 0; ci < 8; ci++) {
#pragma unroll
      for (int kh = 0; kh < 3; kh++) {
        float x10[10];
        float4 xa = *(const float4*)&xs[ci][ph+kh][pw0];
        float4 xb2 = *(const float4*)&xs[ci][ph+kh][pw0+4];
        x10[0]=xa.x; x10[1]=xa.y; x10[2]=xa.z; x10[3]=xa.w;
        x10[4]=xb2.x; x10[5]=xb2.y; x10[6]=xb2.z; x10[7]=xb2.w;
        x10[8]=xs[ci][ph+kh][pw0+8]; x10[9]=xs[ci][ph+kh][pw0+9];
#pragma unroll
        for (int kw = 0; kw < 3; kw++) {
          float4 wv = *(const float4*)&wsm[ci][kh*3+kw][oc_t*4];
#pragma unroll
          for (int m = 0; m < 8; m++) {
            float xv = x10[kw+m];
            acc[0][m] += wv.x*xv; acc[1][m] += wv.y*xv;
            acc[2][m] += wv.z*xv; acc[3][m] += wv.w*xv;
          }
        }
      }
    }
  }
#pragma unroll
  for (int o = 0; o < 4; o++) {
    int oc = oc0 + oc_t*4 + o;
    float bias = ws[OFF_BIAS2 + oc];
    float4 r0, r1;
    r0.x = fmaxf(acc[o][0]+bias, 0.f); r0.y = fmaxf(acc[o][1]+bias, 0.f);
    r0.z = fmaxf(acc[o][2]+bias, 0.f); r0.w = fmaxf(acc[o][3]+bias, 0.f);
    r1.x = fmaxf(acc[o][4]+bias, 0.f); r1.y = fmaxf(acc[o][5]+bias, 0.f);
    r1.z = fmaxf(acc[o][6]+bias, 0.f); r1.w = fmaxf(acc[o][7]+bias, 0.f);
    float* dst = outX + (size_t)oc*HWSZ + (h0+ph)*WW + w0 + pw0;
    *(float4*)dst = r0; *(float4*)(dst+4) = r1;
  }
}

// ---------------- linear + ReLU -> Z -------------------------------------------
__launch_bounds__(256)
__global__ void linear_kernel(const float* __restrict__ pcd,
                              const float* __restrict__ ws,
                              const float* __restrict__ lin_b,
                              float* __restrict__ Z) {
  __shared__ __align__(16) float Mt[128][132];
  __shared__ __align__(16) float zs[16][132];
  const int b = blockIdx.x, t = threadIdx.x;
  const int n0 = b * 16;
#pragma unroll
  for (int i = 0; i < 16; i++) {
    int idx = t + i*256; int r = idx >> 5; int c4 = (idx & 31)*4;
    *(float4*)&Mt[r][c4] = *(const float4*)&ws[OFF_LWT + r*128 + c4];
  }
#pragma unroll
  for (int i = 0; i < 2; i++) {
    int idx = t + i*256; int r = idx >> 5; int c4 = (idx & 31)*4;
    *(float4*)&zs[r][c4] = *(const float4*)&pcd[(size_t)(n0+r)*128 + c4];
  }
  __syncthreads();
  const int nl = t & 15;
  const int c0 = (t >> 4) * 8;
  float acc[8];
#pragma unroll
  for (int q = 0; q < 8; q++) acc[q] = 0.f;
#pragma unroll 8
  for (int k = 0; k < 128; k++) {
    float z = zs[nl][k];
    float4 wa = *(const float4*)&Mt[k][c0];
    float4 wb = *(const float4*)&Mt[k][c0+4];
    acc[0]+=z*wa.x; acc[1]+=z*wa.y; acc[2]+=z*wa.z; acc[3]+=z*wa.w;
    acc[4]+=z*wb.x; acc[5]+=z*wb.y; acc[6]+=z*wb.z; acc[7]+=z*wb.w;
  }
  float4 ba = *(const float4*)&lin_b[c0];
  float4 bb = *(const float4*)&lin_b[c0+4];
  float4 r0, r1;
  r0.x = fmaxf(acc[0]+ba.x,0.f); r0.y = fmaxf(acc[1]+ba.y,0.f);
  r0.z = fmaxf(acc[2]+ba.z,0.f); r0.w = fmaxf(acc[3]+ba.w,0.f);
  r1.x = fmaxf(acc[4]+bb.x,0.f); r1.y = fmaxf(acc[5]+bb.y,0.f);
  r1.z = fmaxf(acc[6]+bb.z,0.f); r1.w = fmaxf(acc[7]+bb.w,0.f);
  float* dst = Z + (size_t)(n0+nl)*128 + c0;
  *(float4*)dst = r0; *(float4*)(dst+4) = r1;
}

// ---------------- gram img via MFMA (runtime chunk; 2-region partials) ---------
__launch_bounds__(256)
__global__ void gram_img_mfma_kernel(const float* __restrict__ X,
                                     const u16* __restrict__ xb,
                                     float* __restrict__ part,
                                     float* __restrict__ part2,
                                     float* __restrict__ psums,
                                     float* __restrict__ psums2,
                                     int chunk, int ntiles) {
  __shared__ __align__(16) u16 tile[128*64];   // [c][px64] bf16, XOR-swizzled
  const int b = blockIdx.x, t = threadIdx.x;
  const int px0 = b * chunk;
  const int wv = t >> 6, l = t & 63;
  const int i0 = (wv >> 1) * 64, j0 = (wv & 1) * 64;
  const int row16 = l & 15, kq = l >> 4;
  const int pg = t & 15;
  const int g0 = t >> 4;
  const int cb16 = t >> 1, hb16 = t & 1;
  float csum[8];
#pragma unroll
  for (int q = 0; q < 8; ++q) csum[q] = 0.f;
  f32x4 acc[4][4];
#pragma unroll
  for (int a = 0; a < 4; ++a)
#pragma unroll
    for (int q = 0; q < 4; ++q) acc[a][q] = (f32x4){0.f,0.f,0.f,0.f};

  if (xb) {
    uint4 vcur[4];
#pragma unroll
    for (int gi = 0; gi < 4; ++gi) {
      int g = hb16*4 + gi;
      vcur[gi] = *(const uint4*)(xb + (size_t)cb16*HWSZ + px0 + g*8);
    }
#pragma unroll 1
    for (int ti = 0; ti < ntiles; ++ti) {
      __syncthreads();   // previous MFMA done reading tile
#pragma unroll
      for (int gi = 0; gi < 4; ++gi) {
        int g = hb16*4 + gi;
        *(uint4*)((char*)tile + cb16*128 + ((g*16) ^ ((cb16 & 7) << 4))) = vcur[gi];
        const u16* p16 = (const u16*)&vcur[gi];
#pragma unroll
        for (int j = 0; j < 8; ++j) csum[0] += from_bf16(p16[j]);
      }
      uint4 vnext[4];
#pragma unroll
      for (int gi = 0; gi < 4; ++gi) {
        int g = hb16*4 + gi;
        int plg = (ti+1)*64 + g*8;
        if (ti < ntiles-1 && plg < chunk)
          vnext[gi] = *(const uint4*)(xb + (size_t)cb16*HWSZ + px0 + plg);
        else
          vnext[gi] = make_uint4(0u,0u,0u,0u);
      }
      __syncthreads();
#pragma unroll
      for (int f = 0; f < 2; ++f) {
        bf16x8 Af[4], Bf[4];
#pragma unroll
        for (int mt = 0; mt < 4; ++mt) {
          int c = i0 + mt*16 + row16;
          Af[mt] = *(const bf16x8*)((char*)tile + c*128 + ((f*64 + kq*16) ^ ((c & 7) << 4)));
        }
#pragma unroll
        for (int nt = 0; nt < 4; ++nt) {
          int c = j0 + nt*16 + row16;
          Bf[nt] = *(const bf16x8*)((char*)tile + c*128 + ((f*64 + kq*16) ^ ((c & 7) << 4)));
        }
#pragma unroll
        for (int mt = 0; mt < 4; ++mt)
#pragma unroll
          for (int nt = 0; nt < 4; ++nt)
            acc[mt][nt] = __builtin_amdgcn_mfma_f32_16x16x32_bf16(Af[mt], Bf[nt], acc[mt][nt], 0, 0, 0);
      }
#pragma unroll
      for (int gi = 0; gi < 4; ++gi) vcur[gi] = vnext[gi];
    }
  } else {
#pragma unroll 1
    for (int ti = 0; ti < ntiles; ++ti) {
      const int plg = ti*64 + pg*4;
      float4 v[8];
      if ((ti+1)*64 <= chunk) {
#pragma unroll
        for (int cc = 0; cc < 8; ++cc) {
          int c = g0 + cc*16;
          v[cc] = *(const float4*)(X + (size_t)c*HWSZ + px0 + plg);
        }
      } else {
#pragma unroll
        for (int cc = 0; cc < 8; ++cc) {
          int c = g0 + cc*16;
          const float* src = X + (size_t)c*HWSZ + px0;
#pragma unroll
          for (int j = 0; j < 4; ++j) {
            int p = plg + j;
            ((float*)&v[cc])[j] = (p < chunk) ? src[p] : 0.f;
          }
        }
      }
      __syncthreads();
#pragma unroll
      for (int cc = 0; cc < 8; ++cc) {
        int c = g0 + cc*16;
        csum[cc] += v[cc].x + v[cc].y + v[cc].z + v[cc].w;
        u32 w0 = pack_bf16(v[cc].x, v[cc].y);
        u32 w1 = pack_bf16(v[cc].z, v[cc].w);
        *(uint2*)((char*)tile + c*128 + ((pg*8) ^ ((c & 7) << 4))) = make_uint2(w0, w1);
      }
      __syncthreads();
#pragma unroll
      for (int f = 0; f < 2; ++f) {
        bf16x8 Af[4], Bf[4];
#pragma unroll
        for (int mt = 0; mt < 4; ++mt) {
          int c = i0 + mt*16 + row16;
          Af[mt] = *(const bf16x8*)((char*)tile + c*128 + ((f*64 + kq*16) ^ ((c & 7) << 4)));
        }
#pragma unroll
        for (int nt = 0; nt < 4; ++nt) {
          int c = j0 + nt*16 + row16;
          Bf[nt] = *(const bf16x8*)((char*)tile + c*128 + ((f*64 + kq*16) ^ ((c & 7) << 4)));
        }
#pragma unroll
        for (int mt = 0; mt < 4; ++mt)
#pragma unroll
          for (int nt = 0; nt < 4; ++nt)
            acc[mt][nt] = __builtin_amdgcn_mfma_f32_16x16x32_bf16(Af[mt], Bf[nt], acc[mt][nt], 0, 0, 0);
      }
      __syncthreads();
    }
  }
  float* pd = (b < 256) ? (psums + (size_t)b*128) : (psums2 + (size_t)(b-256)*128);
  if (xb) {
    float s = csum[0];
    s += __shfl_xor(s, 1, 64);
    if ((t & 1) == 0) pd[cb16] = s;
  } else {
#pragma unroll
    for (int cc = 0; cc < 8; ++cc) {
      float s = csum[cc];
      s += __shfl_xor(s, 1, 64);
      s += __shfl_xor(s, 2, 64);
      s += __shfl_xor(s, 4, 64);
      s += __shfl_xor(s, 8, 64);
      if (pg == 0) pd[g0 + cc*16] = s;
    }
  }
  float* dst = (b < 256) ? (part + (size_t)b*16384) : (part2 + (size_t)(b-256)*16384);
#pragma unroll
  for (int mt = 0; mt < 4; ++mt)
#pragma unroll
    for (int nt = 0; nt < 4; ++nt) {
#pragma unroll
      for (int r = 0; r < 4; ++r) {
        int i = i0 + mt*16 + kq*4 + r;
        int j = j0 + nt*16 + row16;
        dst[i*128 + j] = acc[mt][nt][r];
      }
    }
}

// ---------------- gram pcd (fp32) + fused channel partial sums -----------------
__launch_bounds__(256)
__global__ void gram_pcd_kernel(const float* __restrict__ Z, float* __restrict__ part,
                                float* __restrict__ psums_p) {
  __shared__ __align__(16) float zt[64][132];
  __shared__ float ps4[4][32][4];
  const int b = blockIdx.x, t = threadIdx.x;
  const int n0 = b * CHUNK_P;
  const int i0 = (t >> 4) * 8, j0 = (t & 15) * 8;
  float acc[8][8];
#pragma unroll
  for (int a = 0; a < 8; a++)
#pragma unroll
    for (int q = 0; q < 8; q++) acc[a][q] = 0.f;
  float fsum[4] = {0.f, 0.f, 0.f, 0.f};
  for (int tile = 0; tile < 6; tile++) {
    __syncthreads();
#pragma unroll
    for (int i = 0; i < 8; i++) {
      int idx = t + i*256; int r = idx >> 5; int c4 = (idx & 31)*4;
      int lrow = tile*64 + r;
      int n = n0 + lrow;
      float4 v = {0.f,0.f,0.f,0.f};
      if (lrow < CHUNK_P && n < NPC) v = *(const float4*)&Z[(size_t)n*128 + c4];
      *(float4*)&zt[r][c4] = v;
      fsum[0] += v.x; fsum[1] += v.y; fsum[2] += v.z; fsum[3] += v.w;
    }
    __syncthreads();
#pragma unroll 4
    for (int n = 0; n < 64; n++) {
      float4 a0 = *(const float4*)&zt[n][i0];
      float4 a1 = *(const float4*)&zt[n][i0+4];
      float4 b0 = *(const float4*)&zt[n][j0];
      float4 b1 = *(const float4*)&zt[n][j0+4];
      float av[8] = {a0.x,a0.y,a0.z,a0.w,a1.x,a1.y,a1.z,a1.w};
      float bv[8] = {b0.x,b0.y,b0.z,b0.w,b1.x,b1.y,b1.z,b1.w};
#pragma unroll
      for (int a = 0; a < 8; a++)
#pragma unroll
        for (int q = 0; q < 8; q++) acc[a][q] += av[a]*bv[q];
    }
  }
  float* dst = part + (size_t)b*16384;
#pragma unroll
  for (int a = 0; a < 8; a++) {
    float4 w0v = {acc[a][0],acc[a][1],acc[a][2],acc[a][3]};
    float4 w1v = {acc[a][4],acc[a][5],acc[a][6],acc[a][7]};
    *(float4*)&dst[(i0+a)*128 + j0] = w0v;
    *(float4*)&dst[(i0+a)*128 + j0 + 4] = w1v;
  }
  const int wv2 = t >> 6;
#pragma unroll
  for (int j2 = 0; j2 < 4; ++j2) fsum[j2] += __shfl_down(fsum[j2], 32, 64);
  if ((t & 63) < 32) {
#pragma unroll
    for (int j2 = 0; j2 < 4; ++j2) ps4[wv2][t & 31][j2] = fsum[j2];
  }
  __syncthreads();
  if (t < 128) {
    float s = ps4[0][t>>2][t&3] + ps4[1][t>>2][t&3]
            + ps4[2][t>>2][t&3] + ps4[3][t>>2][t&3];
    psums_p[b*128 + t] = s;
  }
}

// ---------------- channel sums: 4 p-groups x 128 j, unroll-8 ILP ---------------
__launch_bounds__(512)
__global__ void sums_kernel(float* __restrict__ ws, int nparts_img) {
  const int b = blockIdx.x, t = threadIdx.x;
  const int g = t >> 7, j = t & 127;
  __shared__ float red[4][128];
  float a[8];
#pragma unroll
  for (int u = 0; u < 8; ++u) a[u] = 0.f;
  if (b == 0) {
    const int per = nparts_img >> 2;
    const int p0 = g * per;
    for (int k = 0; k < per; k += 8) {
#pragma unroll
      for (int u = 0; u < 8; ++u) {
        int p = p0 + k + u;
        const float* ps = (p < 256) ? (ws + OFF_PSUMS + (size_t)p*128)
                                    : (ws + OFF_PSUMS2 + (size_t)(p-256)*128);
        a[u] += ps[j];
      }
    }
  } else {
    const int p0 = g * 16;
    for (int k = 0; k < 16; k += 8) {
#pragma unroll
      for (int u = 0; u < 8; ++u)
        a[u] += ws[OFF_PSUMS_P + (size_t)(p0 + k + u)*128 + j];
    }
  }
  float s = ((a[0]+a[1])+(a[2]+a[3])) + ((a[4]+a[5])+(a[6]+a[7]));
  red[g][j] = s;
  __syncthreads();
  if (g == 0)
    ws[(b == 0 ? OFF_SUMS_IMG : OFF_SUMS_PCD) + j] =
        (red[0][j] + red[1][j]) + (red[2][j] + red[3][j]);
}

// ------- reduce partials -> cov: 4 p-groups x 128 j per row, unroll-8 ILP ------
__launch_bounds__(512)
__global__ void reduce_cov_kernel(float* __restrict__ ws, int nparts_img) {
  const int b = blockIdx.x, t = threadIdx.x;
  const int g = t >> 7, j = t & 127;
  const bool isimg = (b < 128);
  const int i = isimg ? b : b - 128;
  __shared__ float red[4][128];
  float a[8];
#pragma unroll
  for (int u = 0; u < 8; ++u) a[u] = 0.f;
  if (isimg) {
    const int per = nparts_img >> 2;
    const int p0 = g * per;
    for (int k = 0; k < per; k += 8) {
#pragma unroll
      for (int u = 0; u < 8; ++u) {
        int p = p0 + k + u;
        const float* part = (p < 256) ? (ws + OFF_PART_IMG + (size_t)p*16384)
                                      : (ws + OFF_PART2 + (size_t)(p-256)*16384);
        a[u] += part[i*128 + j];
      }
    }
  } else {
    const int p0 = g * 16;
    for (int k = 0; k < 16; k += 8) {
#pragma unroll
      for (int u = 0; u < 8; ++u)
        a[u] += ws[OFF_PART_PCD + (size_t)(p0 + k + u)*16384 + i*128 + j];
    }
  }
  float s = ((a[0]+a[1])+(a[2]+a[3])) + ((a[4]+a[5])+(a[6]+a[7]));
  red[g][j] = s;
  __syncthreads();
  if (g == 0) {
    float gsum = (red[0][j] + red[1][j]) + (red[2][j] + red[3][j]);
    const int so = isimg ? OFF_SUMS_IMG : OFF_SUMS_PCD;
    float Si = ws[so + i];
    float Sj = ws[so + j];
    float n = isimg ? (float)HWSZ : (float)NPC;
    float cov = (gsum - Si*Sj/n) / (n - 1.f);
    ws[(isimg ? OFF_COV_IMG : OFF_COV_PCD) + i*128 + j] = cov;
  }
}

// ---------------- blocked Gauss-Jordan inverse (panel=16) ----------------------
__launch_bounds__(256, 1)
__global__ void invert_kernel(float* __restrict__ ws) {
  __shared__ float A_[128*132];     // 67584 B
  __shared__ float Rb_[16*132];     // 8448 B
  __shared__ float prw[16];
  __shared__ float pcl[16];
  const int blk = blockIdx.x, t = threadIdx.x;
  const float* src = ws + (blk == 0 ? OFF_COV_IMG : OFF_COV_PCD);
  float* dst = ws + (blk == 0 ? OFF_INV_IMG : OFF_INV_PCD);
  for (int e = t; e < 16384; e += 256) {
    int i = e >> 7, j = e & 127;
    A_[i*132 + j] = src[e] + ((i == j) ? 1e-6f : 0.f);
  }
#pragma unroll 1
  for (int p = 0; p < 8; ++p) {
    const int k0 = p * 16;
    __syncthreads();
    if (t < 64) {
      const int r = t & 15, cg = t >> 4, cb = cg * 4;
      float4 d = *(const float4*)&A_[(k0 + r)*132 + k0 + cb];
#pragma unroll 1
      for (int k = 0; k < 16; ++k) {
        const int kg = k >> 2, km = k & 3;
        if (r == k) {
          prw[cb+0] = d.x; prw[cb+1] = d.y; prw[cb+2] = d.z; prw[cb+3] = d.w;
        }
        if (cg == kg) {
          float el = (km==0) ? d.x : (km==1) ? d.y : (km==2) ? d.z : d.w;
          pcl[r] = el;
        }
        __builtin_amdgcn_wave_barrier();
        float ip = 1.f / pcl[k];
        float f  = pcl[r];
        float p0 = prw[cb+0], p1 = prw[cb+1], p2 = prw[cb+2], p3 = prw[cb+3];
        __builtin_amdgcn_wave_barrier();
        if (r == k) {
          d.x *= ip; d.y *= ip; d.z *= ip; d.w *= ip;
          if (cg == kg) { if (km==0) d.x=ip; else if (km==1) d.y=ip; else if (km==2) d.z=ip; else d.w=ip; }
        } else {
          float g = f * ip;
          d.x -= g*p0; d.y -= g*p1; d.z -= g*p2; d.w -= g*p3;
          if (cg == kg) { if (km==0) d.x=-g; else if (km==1) d.y=-g; else if (km==2) d.z=-g; else d.w=-g; }
        }
        __builtin_amdgcn_wave_barrier();
      }
      *(float4*)&Rb_[r*132 + k0 + cb] = d;
    }
    __syncthreads();
    {
      const int r = t & 15, ch = t >> 4;
      if ((ch >> 1) != p) {
        const int j0 = ch * 8;
        float4 dv0 = *(const float4*)&Rb_[r*132 + k0];
        float4 dv1 = *(const float4*)&Rb_[r*132 + k0 + 4];
        float4 dv2 = *(const float4*)&Rb_[r*132 + k0 + 8];
        float4 dv3 = *(const float4*)&Rb_[r*132 + k0 + 12];
        float dv[16] = {dv0.x,dv0.y,dv0.z,dv0.w, dv1.x,dv1.y,dv1.z,dv1.w,
                        dv2.x,dv2.y,dv2.z,dv2.w, dv3.x,dv3.y,dv3.z,dv3.w};
        float4 a0 = {0,0,0,0}, a1 = {0,0,0,0};
#pragma unroll
        for (int s = 0; s < 16; ++s) {
          float4 r0v = *(const float4*)&A_[(k0+s)*132 + j0];
          float4 r1v = *(const float4*)&A_[(k0+s)*132 + j0 + 4];
          float w = dv[s];
          a0.x += w*r0v.x; a0.y += w*r0v.y; a0.z += w*r0v.z; a0.w += w*r0v.w;
          a1.x += w*r1v.x; a1.y += w*r1v.y; a1.z += w*r1v.z; a1.w += w*r1v.w;
        }
        *(float4*)&Rb_[r*132 + j0] = a0;
        *(float4*)&Rb_[r*132 + j0 + 4] = a1;
      }
    }
    __syncthreads();
    {
      const int tr = t >> 4, tc = t & 15;
      const int r0 = tr * 8, c0 = tc * 8;
      const bool pivrow = (tr >> 1) == p;
      const bool pivcol = (tc >> 1) == p;
      float4 acc[8][2];
      float4 F4[8][4];
      if (pivrow) {
#pragma unroll
        for (int i = 0; i < 8; ++i) {
          acc[i][0] = *(const float4*)&Rb_[(r0 + i - k0)*132 + c0];
          acc[i][1] = *(const float4*)&Rb_[(r0 + i - k0)*132 + c0 + 4];
        }
      } else {
#pragma unroll
        for (int i = 0; i < 8; ++i) {
          F4[i][0] = *(const float4*)&A_[(r0+i)*132 + k0];
          F4[i][1] = *(const float4*)&A_[(r0+i)*132 + k0 + 4];
          F4[i][2] = *(const float4*)&A_[(r0+i)*132 + k0 + 8];
          F4[i][3] = *(const float4*)&A_[(r0+i)*132 + k0 + 12];
        }
        if (pivcol) {
#pragma unroll
          for (int i = 0; i < 8; ++i) {
            acc[i][0] = make_float4(0.f,0.f,0.f,0.f);
            acc[i][1] = make_float4(0.f,0.f,0.f,0.f);
          }
        } else {
#pragma unroll
          for (int i = 0; i < 8; ++i) {
            acc[i][0] = *(const float4*)&A_[(r0+i)*132 + c0];
            acc[i][1] = *(const float4*)&A_[(r0+i)*132 + c0 + 4];
          }
        }
      }
      __syncthreads();
      if (!pivrow) {
#pragma unroll
        for (int s = 0; s < 16; ++s) {
          float4 rb0 = *(const float4*)&Rb_[s*132 + c0];
          float4 rb1 = *(const float4*)&Rb_[s*132 + c0 + 4];
#pragma unroll
          for (int i = 0; i < 8; ++i) {
            float fs = (s&3)==0 ? F4[i][s>>2].x : (s&3)==1 ? F4[i][s>>2].y
                     : (s&3)==2 ? F4[i][s>>2].z : F4[i][s>>2].w;
            acc[i][0] = f4_fnma(acc[i][0], fs, rb0);
            acc[i][1] = f4_fnma(acc[i][1], fs, rb1);
          }
        }
      }
#pragma unroll
      for (int i = 0; i < 8; ++i) {
        *(float4*)&A_[(r0+i)*132 + c0]     = acc[i][0];
        *(float4*)&A_[(r0+i)*132 + c0 + 4] = acc[i][1];
      }
    }
  }
  __syncthreads();
  for (int e = t; e < 16384; e += 256)
    dst[e] = A_[(e >> 7)*132 + (e & 127)];
}

// ---------------- attention rows -> mix matrices (img: bf16 frags, pcd: MT) ----
__launch_bounds__(128)
__global__ void attn_kernel(float* __restrict__ ws) {
  const int b = blockIdx.x, j = threadIdx.x;
  const bool isimg = (b < 128);
  const int i = isimg ? b : b - 128;
  const float* rowA = ws + (isimg ? OFF_COV_PCD : OFF_COV_IMG) + i*128;
  const float* matA = ws + (isimg ? OFF_INV_IMG : OFF_INV_PCD);
  const float* rowB = ws + (isimg ? OFF_COV_IMG : OFF_COV_PCD) + i*128;
  const float* matB = ws + (isimg ? OFF_COV_IMG : OFF_COV_PCD);
  __shared__ float rA[128], rB[128], red[128];
  rA[j] = rowA[j]; rB[j] = rowB[j];
  __syncthreads();
  float dA = 0.f, dB = 0.f;
#pragma unroll 8
  for (int k = 0; k < 128; ++k) {
    dA += rA[k] * matA[k*128 + j];
    dB += rB[k] * matB[k*128 + j];
  }
  dA *= 0.0078125f; dB *= 0.0078125f;
  red[j] = dA; __syncthreads();
  for (int s2 = 64; s2 > 0; s2 >>= 1) { if (j < s2) red[j] = fmaxf(red[j], red[j+s2]); __syncthreads(); }
  float mA = red[0]; __syncthreads();
  float eA = expf(dA - mA);
  red[j] = eA; __syncthreads();
  for (int s2 = 64; s2 > 0; s2 >>= 1) { if (j < s2) red[j] += red[j+s2]; __syncthreads(); }
  float sA = red[0]; __syncthreads();
  red[j] = dB; __syncthreads();
  for (int s2 = 64; s2 > 0; s2 >>= 1) { if (j < s2) red[j] = fmaxf(red[j], red[j+s2]); __syncthreads(); }
  float mB = red[0]; __syncthreads();
  float eB = expf(dB - mB);
  red[j] = eB; __syncthreads();
  for (int s2 = 64; s2 > 0; s2 >>= 1) { if (j < s2) red[j] += red[j+s2]; __syncthreads(); }
  float sB = red[0]; __syncthreads();
  float m = 0.1f * (eA/sA + eB/sB);   // M[i][j]
  if (isimg) {
    int f = j >> 5, ob = i >> 4, l = ((j >> 3) & 3)*16 + (i & 15), jj = j & 7;
    ((u16*)(ws + OFF_MB))[(f*8 + ob)*512 + l*8 + jj] = to_bf16(m);
  } else {
    ws[OFF_MT_PCD + j*128 + i] = m;   // transposed: MT[k][c]
  }
}

// ---------------- img final via MFMA, two-pass transpose (4 blocks/CU) ---------
__launch_bounds__(256, 4)
__global__ void img_final_mfma_kernel(const float* __restrict__ img_in,
                                      const float* __restrict__ ws,
                                      const u16* __restrict__ xb,
                                      float* __restrict__ io) {
  __shared__ __align__(16) char smem[34816];   // max(bt 32768, ts 34816)
  u16* bt = (u16*)smem;          // [128px][128c] bf16, XOR-swizzled
  float* ts = (float*)smem;      // [128c][68px]
  const int blk = blockIdx.x, t = threadIdx.x;
  const int px0 = blk * 128;
  const int pxg = (t & 31) * 4;
  const int cp0 = t >> 5;
  if (xb) {
#pragma unroll
    for (int cc = 0; cc < 8; ++cc) {
      int cpair = cp0 + cc*8;
      const u16* s0 = xb + (size_t)(2*cpair)*HWSZ + px0 + pxg;
      uint2 ua = *(const uint2*)s0;
      uint2 ub = *(const uint2*)(s0 + HWSZ);
      u32 w[4];
      w[0] = (ua.x & 0xFFFFu) | ((ub.x & 0xFFFFu) << 16);
      w[1] = (ua.x >> 16)     | (ub.x & 0xFFFF0000u);
      w[2] = (ua.y & 0xFFFFu) | ((ub.y & 0xFFFFu) << 16);
      w[3] = (ua.y >> 16)     | (ub.y & 0xFFFF0000u);
#pragma unroll
      for (int j = 0; j < 4; ++j) {
        int pxl = pxg + j;
        *(u32*)((char*)bt + pxl*256 + ((cpair*4) ^ ((pxl & 7) << 4))) = w[j];
      }
    }
  } else {
#pragma unroll
    for (int cc = 0; cc < 8; ++cc) {
      int cpair = cp0 + cc*8;
      const float* s0 = io + (size_t)(2*cpair)*HWSZ + px0 + pxg;
      float4 a = *(const float4*)s0;
      float4 b4 = *(const float4*)(s0 + HWSZ);
#pragma unroll
      for (int j = 0; j < 4; ++j) {
        int pxl = pxg + j;
        *(u32*)((char*)bt + pxl*256 + ((cpair*4) ^ ((pxl & 7) << 4))) =
            pack_bf16(((const float*)&a)[j], ((const float*)&b4)[j]);
      }
    }
  }
  __syncthreads();
  const int wv = t >> 6, l = t & 63;
  const int i0 = (wv >> 1) * 64, j0 = (wv & 1) * 64;
  const int row16 = l & 15, kq = l >> 4;
  const u16* Mbf = (const u16*)(ws + OFF_MB);
  f32x4 acc[4][4];
#pragma unroll
  for (int a = 0; a < 4; ++a)
#pragma unroll
    for (int q = 0; q < 4; ++q) acc[a][q] = (f32x4){0.f,0.f,0.f,0.f};
#pragma unroll
  for (int f = 0; f < 4; ++f) {
    bf16x8 Bf[4], Am[4];
#pragma unroll
    for (int nt = 0; nt < 4; ++nt) {
      int pxl = j0 + nt*16 + row16;
      Bf[nt] = *(const bf16x8*)((char*)bt + pxl*256 + ((f*64 + kq*16) ^ ((pxl & 7) << 4)));
    }
#pragma unroll
    for (int mt = 0; mt < 4; ++mt) {
      int ob = (wv >> 1) * 4 + mt;
      Am[mt] = *(const bf16x8*)(Mbf + (f*8 + ob)*512 + l*8);
    }
#pragma unroll
    for (int mt = 0; mt < 4; ++mt)
#pragma unroll
      for (int nt = 0; nt < 4; ++nt)
        acc[mt][nt] = __builtin_amdgcn_mfma_f32_16x16x32_bf16(Am[mt], Bf[nt], acc[mt][nt], 0, 0, 0);
  }
#pragma unroll 1
  for (int half = 0; half < 2; ++half) {
    __syncthreads();
    if ((wv & 1) == half) {
#pragma unroll
      for (int mt = 0; mt < 4; ++mt)
#pragma unroll
        for (int nt = 0; nt < 4; ++nt) {
          int lpx = nt*16 + row16;
#pragma unroll
          for (int r = 0; r < 4; ++r) {
            int c = i0 + mt*16 + kq*4 + r;
            ts[c*68 + lpx] = acc[mt][nt][r];
          }
        }
    }
    __syncthreads();
    const int cq = t >> 2, p4 = (t & 3) * 4;
#pragma unroll
    for (int cp = 0; cp < 2; ++cp) {
      int c = cp*64 + cq;
#pragma unroll
      for (int j = 0; j < 4; ++j) {
        int lpx = p4 + j*16;
        float4 v = *(const float4*)&ts[c*68 + lpx];
        size_t off = (size_t)c*HWSZ + px0 + half*64 + lpx;
        float4 o = *(const float4*)&img_in[off];
        float4 r;
        r.x = v.x + 0.8f*o.x; r.y = v.y + 0.8f*o.y;
        r.z = v.z + 0.8f*o.z; r.w = v.w + 0.8f*o.w;
        *(float4*)&io[off] = r;
      }
    }
  }
}

// ---------------- pcd final: Z = Z @ M_pcd^T + 0.8*pcd (in place) --------------
__launch_bounds__(256)
__global__ void pcd_final_kernel(const float* __restrict__ pcd_in,
                                 const float* __restrict__ ws,
                                 float* __restrict__ Z) {
  __shared__ __align__(16) float Mt[128][132];
  __shared__ __align__(16) float zs[16][132];
  const int b = blockIdx.x, t = threadIdx.x;
  const int n0 = b * 16;
#pragma unroll
  for (int i = 0; i < 16; i++) {
    int idx = t + i*256; int r = idx >> 5; int c4 = (idx & 31)*4;
    *(float4*)&Mt[r][c4] = *(const float4*)&ws[OFF_MT_PCD + r*128 + c4];
  }
#pragma unroll
  for (int i = 0; i < 2; i++) {
    int idx = t + i*256; int r = idx >> 5; int c4 = (idx & 31)*4;
    *(float4*)&zs[r][c4] = *(const float4*)&Z[(size_t)(n0+r)*128 + c4];
  }
  __syncthreads();
  const int nl = t & 15;
  const int c0 = (t >> 4) * 8;
  float acc[8];
#pragma unroll
  for (int q = 0; q < 8; q++) acc[q] = 0.f;
#pragma unroll 8
  for (int k = 0; k < 128; k++) {
    float z = zs[nl][k];
    float4 wa = *(const float4*)&Mt[k][c0];
    float4 wb = *(const float4*)&Mt[k][c0+4];
    acc[0]+=z*wa.x; acc[1]+=z*wa.y; acc[2]+=z*wa.z; acc[3]+=z*wa.w;
    acc[4]+=z*wb.x; acc[5]+=z*wb.y; acc[6]+=z*wb.z; acc[7]+=z*wb.w;
  }
  size_t off = (size_t)(n0+nl)*128 + c0;
  float4 pa = *(const float4*)&pcd_in[off];
  float4 pb = *(const float4*)&pcd_in[off+4];
  float4 r0, r1;
  r0.x = acc[0] + 0.8f*pa.x; r0.y = acc[1] + 0.8f*pa.y;
  r0.z = acc[2] + 0.8f*pa.z; r0.w = acc[3] + 0.8f*pa.w;
  r1.x = acc[4] + 0.8f*pb.x; r1.y = acc[5] + 0.8f*pb.y;
  r1.z = acc[6] + 0.8f*pb.z; r1.w = acc[7] + 0.8f*pb.w;
  *(float4*)&Z[off] = r0; *(float4*)&Z[off+4] = r1;
}

extern "C" void kernel_launch(void* const* d_in, const int* in_sizes, int n_in,
                              void* d_out, int out_size, void* d_ws, size_t ws_size,
                              hipStream_t stream) {
  (void)in_sizes; (void)n_in; (void)out_size;
  const float* img_in = (const float*)d_in[0];
  const float* pcd_in = (const float*)d_in[1];
  const float* conv_w = (const float*)d_in[2];
  const float* conv_b = (const float*)d_in[3];
  const float* gamma  = (const float*)d_in[4];
  const float* beta   = (const float*)d_in[5];
  const float* mean   = (const float*)d_in[6];
  const float* var    = (const float*)d_in[7];
  const float* lin_w  = (const float*)d_in[8];
  const float* lin_b  = (const float*)d_in[9];
  float* out = (float*)d_out;
  float* X = out;            // [128][307200] conv output (fp32 path)
  float* Z = out + IMG_SZ;   // [22432][128] linear output, transformed in place
  float* ws = (float*)d_ws;
  const int big  = (ws_size >= (size_t)WS_NEED_FLOATS * 4) ? 1 : 0;
  const int big2 = (ws_size >= (size_t)WS_NEED2_FLOATS * 4) ? 1 : 0;
  u16* Xb = big2 ? (u16*)(ws + OFF_XB) : (u16*)nullptr;

  hipLaunchKernelGGL(prep_kernel, dim3(64), dim3(256), 0, stream,
                     conv_w, conv_b, gamma, beta, mean, var, lin_w, ws, big);
  if (big) {
    u16* Timg = (u16*)(ws + OFF_TIMG_F);
    u16* Wf = (u16*)(ws + OFF_WB);
    hipLaunchKernelGGL(timg_kernel, dim3(4941), dim3(256), 0, stream, img_in, Timg);
    hipLaunchKernelGGL(conv_mfma11_kernel, dim3(2400), dim3(256), 0, stream, Timg, Wf, ws, X, Xb);
  } else {
    hipLaunchKernelGGL(conv_kernel, dim3(4800), dim3(256), 0, stream, img_in, ws, X);
  }
  hipLaunchKernelGGL(linear_kernel, dim3(NPC/16), dim3(256), 0, stream, pcd_in, ws, lin_b, Z);
  // gram_img: big path uses 512 chunks of 600 px (2 blocks/CU); partials for
  // blocks >=256 alias the dead Timg region (rewritten by timg each replay).
  {
    int nbi    = big ? 512 : 256;
    int chunk  = big ? 600 : 1200;
    int ntiles = big ? 10  : 19;
    hipLaunchKernelGGL(gram_img_mfma_kernel, dim3(nbi), dim3(256), 0, stream,
                       X, Xb, ws + OFF_PART_IMG, ws + OFF_PART2,
                       ws + OFF_PSUMS, ws + OFF_PSUMS2, chunk, ntiles);
    hipLaunchKernelGGL(gram_pcd_kernel, dim3(NBP), dim3(256), 0, stream,
                       Z, ws + OFF_PART_PCD, ws + OFF_PSUMS_P);
    hipLaunchKernelGGL(sums_kernel, dim3(2), dim3(512), 0, stream, ws, nbi);
    hipLaunchKernelGGL(reduce_cov_kernel, dim3(256), dim3(512), 0, stream, ws, nbi);
  }
  hipLaunchKernelGGL(invert_kernel, dim3(2), dim3(256), 0, stream, ws);
  hipLaunchKernelGGL(attn_kernel, dim3(256), dim3(128), 0, stream, ws);
  hipLaunchKernelGGL(img_final_mfma_kernel, dim3(HWSZ/128), dim3(256), 0, stream,
                     img_in, ws, Xb, X);
  hipLaunchKernelGGL(pcd_final_kernel, dim3(NPC/16), dim3(256), 0, stream, pcd_in, ws, Z);
}